// Round 15
// baseline (105.166 us; speedup 1.0000x reference)
//
#include <hip/hip_runtime.h>

// Problem dims (fixed by reference)
#define BATCH  4096
#define IN_DIM 256
#define HID    512
#define NCOL   8192            // HID * STATES

// Main tiling: 128x64 block tile, 4 waves stacked on M (32 rows each)
#define BM 128
#define BN 64

typedef __attribute__((ext_vector_type(8))) short bf16x8;
typedef __attribute__((ext_vector_type(4))) float f32x4;
typedef __attribute__((ext_vector_type(4))) float fvec4;   // clang-native, nt-compatible

typedef __attribute__((address_space(1))) const unsigned as1_uint;
typedef __attribute__((address_space(3))) unsigned       as3_uint;

// pack bf16(f0) into low16, bf16(f1) into high16 (truncation) — 1 v_perm_b32
__device__ __forceinline__ uint pack_hi(float f0, float f1) {
    return __builtin_amdgcn_perm(__builtin_bit_cast(uint, f1),
                                 __builtin_bit_cast(uint, f0), 0x07060302u);
}
__device__ __forceinline__ float hi_part(float f) {
    return __builtin_bit_cast(float, __builtin_bit_cast(uint, f) & 0xFFFF0000u);
}
__device__ __forceinline__ float tanh_fast(float x) {
    float e = __builtin_amdgcn_exp2f(x * 2.8853900817779268f); // 2*log2(e)
    float r = __builtin_amdgcn_rcpf(e + 1.0f);
    return __builtin_fmaf(-2.0f, r, 1.0f);
}
// split f[0..7] (k-consecutive) into hi/lo bf16x8 fragments
__device__ __forceinline__ void split8(const float* f, uint4& h, uint4& l) {
    h.x = pack_hi(f[0], f[1]); h.y = pack_hi(f[2], f[3]);
    h.z = pack_hi(f[4], f[5]); h.w = pack_hi(f[6], f[7]);
    l.x = pack_hi(f[0] - hi_part(f[0]), f[1] - hi_part(f[1]));
    l.y = pack_hi(f[2] - hi_part(f[2]), f[3] - hi_part(f[3]));
    l.z = pack_hi(f[4] - hi_part(f[4]), f[5] - hi_part(f[5]));
    l.w = pack_hi(f[6] - hi_part(f[6]), f[7] - hi_part(f[7]));
}

// Workspace layout (ushort elements):
//  whi [0, 2097152)  wlo [2097152, 4194304)   - 8192n x 256k, tiled
// tile layout: plane[((n>>4)*32 + koct)*128 + (n&15)*8 + j], k = koct*8+j
#define W_ELEMS  2097152
#define WS_NEED  (8u * 1024u * 1024u)

// ---- prep W: [k][n] f32 -> fragment-ready tiled bf16 hi/lo ----
__global__ __launch_bounds__(256) void prep_w_kernel(
    const float* __restrict__ W, ushort* __restrict__ whi, ushort* __restrict__ wlo)
{
    const int n    = blockIdx.x * 256 + threadIdx.x;   // 0..8191
    const int koct = blockIdx.y;                       // 0..31
    float f[8];
    #pragma unroll
    for (int j = 0; j < 8; ++j)
        f[j] = __builtin_nontemporal_load(&W[(size_t)(koct * 8 + j) * NCOL + n]);
    uint4 h, l;
    split8(f, h, l);
    const size_t o = ((size_t)((n >> 4) * 32 + koct) * 16 + (n & 15)) * 8;
    *(uint4*)(whi + o) = h;
    *(uint4*)(wlo + o) = l;
}

// ---- main: B via LDS DMA, A = x loaded f32 + converted in-register (prep_x
//      folded in; x is L2-resident per-XCD with the row-clustered mapping) ----
// __launch_bounds__(256,3): cap ~170 regs. r13 A/B: (256,4)'s 128 cap regressed
// the bench. r4: (256,8) spills. r12: dual-tile accumulators spill.
// out_mean store CACHED (r8: nt on 4B scalars = 8-16x write amplification).
// hq loads CACHED. out_new store nt (r11/r13 A/B: nt wins the bench — cached
// writeback evicts hq from L3 between graph replays, +50MB refetch).
__global__ __launch_bounds__(256, 3) void mqc_main_kernel(
    const float* __restrict__ x,
    const ushort* __restrict__ whi, const ushort* __restrict__ wlo,
    const float* __restrict__ hq,
    float* __restrict__ out_mean, float* __restrict__ out_new)
{
    // one k-chunk (16 koct = 128 k) of B fragments: 4 ntiles x 16 kl x 16 l16 x 8
    __shared__ ushort sBh[8192], sBl[8192];    // 16 KiB + 16 KiB

    const int t     = threadIdx.x;
    const int lane  = t & 63;
    const int w     = t >> 6;           // wave 0..3 -> rows w*32..w*32+31
    const int lquad = lane >> 4;        // 0..3
    const int l16   = lane & 15;

    // XCD-clustered bijective block mapping (4096 = 8 xcd * 4 rowg * 128 colg)
    const int wgid = blockIdx.x;
    const int xcd  = wgid & 7;
    const int q    = wgid >> 3;
    const int rowg = (xcd << 2) | (q & 3);   // 0..31
    const int colg = q >> 2;                 // 0..127
    const int row0 = rowg * BM;
    const int col0 = colg * BN;
    const int ntile0 = col0 >> 4;

    f32x4 acc[2][4] = {};               // [mi][ni]; D[n][b]: row=n, col=b

    // Stage one k-chunk of B (both planes, 32 KB) via global_load_lds w16.
    #define STAGE(KOCT0) {                                                          \
        _Pragma("unroll")                                                           \
        for (int itc = 0; itc < 8; ++itc) {                                         \
            const int c  = itc * 4 + w;                                             \
            const int nt = (c >> 2) & 3;                                            \
            const int kl = (c & 3) * 4 + (lane >> 4);                               \
            const ushort* srcp = ((c >> 4) ? wlo : whi)                             \
                + ((size_t)(ntile0 + nt) * 32 + (KOCT0) + kl) * 128 + (lane & 15) * 8; \
            ushort* dstp = ((c >> 4) ? sBl : sBh) + nt * 2048 + (c & 3) * 512;      \
            __builtin_amdgcn_global_load_lds((as1_uint*)srcp, (as3_uint*)dstp,      \
                                             16, 0, 0);                             \
        }                                                                           \
    }

    // A fragments for 2 k-steps (SL0, SL0+1): f32 x loads + in-reg hi/lo split
    #define APREF(AH, AL, KOCT0, SL0) {                                             \
        _Pragma("unroll")                                                           \
        for (int s = 0; s < 2; ++s) {                                               \
            const int koct = (KOCT0) + ((SL0) + s) * 4 + lquad;                     \
            _Pragma("unroll")                                                       \
            for (int mi = 0; mi < 2; ++mi) {                                        \
                const int row = row0 + w * 32 + mi * 16 + l16;                      \
                const float* p = &x[(size_t)row * IN_DIM + koct * 8];               \
                const fvec4 v0 = *(const fvec4*)p;                                  \
                const fvec4 v1 = *(const fvec4*)(p + 4);                            \
                float f[8];                                                         \
                f[0] = v0.x; f[1] = v0.y; f[2] = v0.z; f[3] = v0.w;                 \
                f[4] = v1.x; f[5] = v1.y; f[6] = v1.z; f[7] = v1.w;                 \
                uint4 h_, l_;                                                       \
                split8(f, h_, l_);                                                  \
                AH[s][mi] = __builtin_bit_cast(bf16x8, h_);                         \
                AL[s][mi] = __builtin_bit_cast(bf16x8, l_);                         \
            }                                                                       \
        }                                                                           \
    }

    // 2 MFMA k-steps (SL0, SL0+1) using prefetched A regs + staged B in LDS
    #define KSTEP2(AH, AL, SL0) {                                                   \
        _Pragma("unroll")                                                           \
        for (int s = 0; s < 2; ++s) {                                               \
            const int bidx = (((SL0) + s) * 4 + lquad) * 128 + l16 * 8;             \
            bf16x8 bH[4], bL[4];                                                    \
            _Pragma("unroll")                                                       \
            for (int ni = 0; ni < 4; ++ni) {                                        \
                bH[ni] = *(const bf16x8*)(sBh + ni * 2048 + bidx);                  \
                bL[ni] = *(const bf16x8*)(sBl + ni * 2048 + bidx);                  \
            }                                                                       \
            _Pragma("unroll")                                                       \
            for (int mi = 0; mi < 2; ++mi)                                          \
                _Pragma("unroll")                                                   \
                for (int ni = 0; ni < 4; ++ni)                                      \
                    acc[mi][ni] = __builtin_amdgcn_mfma_f32_16x16x32_bf16(bH[ni], AH[s][mi], acc[mi][ni], 0, 0, 0); \
            _Pragma("unroll")                                                       \
            for (int mi = 0; mi < 2; ++mi)                                          \
                _Pragma("unroll")                                                   \
                for (int ni = 0; ni < 4; ++ni)                                      \
                    acc[mi][ni] = __builtin_amdgcn_mfma_f32_16x16x32_bf16(bH[ni], AL[s][mi], acc[mi][ni], 0, 0, 0); \
            _Pragma("unroll")                                                       \
            for (int mi = 0; mi < 2; ++mi)                                          \
                _Pragma("unroll")                                                   \
                for (int ni = 0; ni < 4; ++ni)                                      \
                    acc[mi][ni] = __builtin_amdgcn_mfma_f32_16x16x32_bf16(bL[ni], AH[s][mi], acc[mi][ni], 0, 0, 0); \
        }                                                                           \
    }

    bf16x8 AaH[2][2], AaL[2][2], AbH[2][2], AbL[2][2];
    fvec4 hv[2][4];

    // ---- chunk 0 (koct 0..15) ----
    STAGE(0);
    APREF(AaH, AaL, 0, 0);          // A for ksteps 0,1 — convert overlaps DMA
    __syncthreads();                // drains DMA
    APREF(AbH, AbL, 0, 2);          // A for ksteps 2,3 — hidden under KSTEP2
    KSTEP2(AaH, AaL, 0);
    KSTEP2(AbH, AbL, 2);
    __syncthreads();                // chunk-0 LDS reads done before overwrite
    // ---- chunk 1 (koct 16..31) ----
    STAGE(16);
    APREF(AaH, AaL, 16, 0);
    __syncthreads();
    APREF(AbH, AbL, 16, 2);
    KSTEP2(AaH, AaL, 0);
    // epilogue hq prefetch (cached): covered by the remaining 48 MFMAs
    #pragma unroll
    for (int mi = 0; mi < 2; ++mi) {
        const int b = row0 + w * 32 + mi * 16 + l16;
        #pragma unroll
        for (int ni = 0; ni < 4; ++ni) {
            const int n = col0 + ni * 16 + lquad * 4;
            hv[mi][ni] = *(const fvec4*)&hq[(size_t)b * NCOL + n];
        }
    }
    KSTEP2(AbH, AbL, 2);
    #undef STAGE
    #undef APREF
    #undef KSTEP2

    // ---- fused epilogue: tanh(C + 0.9*h), nt out_new store, cached out_mean.
    //      D[n][b]: n = col0+ni*16+4*lquad+reg, b = row0+w*32+mi*16+l16
    #pragma unroll
    for (int mi = 0; mi < 2; ++mi) {
        const int b = row0 + w * 32 + mi * 16 + l16;
        #pragma unroll
        for (int ni = 0; ni < 4; ++ni) {
            const int n = col0 + ni * 16 + lquad * 4;
            fvec4 ov;
            ov.x = tanh_fast(__builtin_fmaf(0.9f, hv[mi][ni].x, acc[mi][ni][0]));
            ov.y = tanh_fast(__builtin_fmaf(0.9f, hv[mi][ni].y, acc[mi][ni][1]));
            ov.z = tanh_fast(__builtin_fmaf(0.9f, hv[mi][ni].z, acc[mi][ni][2]));
            ov.w = tanh_fast(__builtin_fmaf(0.9f, hv[mi][ni].w, acc[mi][ni][3]));
            __builtin_nontemporal_store(ov, (fvec4*)&out_new[(size_t)b * NCOL + n]);
            float s = (ov.x + ov.y) + (ov.z + ov.w);
            s += __shfl_xor(s, 16);
            s += __shfl_xor(s, 32);
            if (lquad == 0)
                out_mean[(size_t)b * HID + (col0 >> 4) + ni] = s * 0.0625f;
        }
    }
}

// ================= fallback (round-5 proven kernel, used if ws too small) ======
#define BKF 64
__device__ __forceinline__ int swz(int row, int byteoff) {
    return byteoff ^ ((((row & 7) ^ ((row >> 3) & 7))) << 4);
}
__global__ __launch_bounds__(256, 4) void mqc_fallback_kernel(
    const float* __restrict__ x, const float* __restrict__ hq,
    const float* __restrict__ W,
    float* __restrict__ out_mean, float* __restrict__ out_new)
{
    __shared__ char sB[2 * BN * BKF * 2];
    char* const sB_hi = sB;
    char* const sB_lo = sB + BN * BKF * 2;
    const int t = threadIdx.x, lane = t & 63, w = t >> 6;
    const int lquad = lane >> 4, l16 = lane & 15;
    const int row0 = blockIdx.x * BM, col0 = blockIdx.y * BN;
    const int k0 = (t >> 4) * 4, n0 = (t & 15) * 4;
    f32x4 acc[2][4] = {};
    for (int kt = 0; kt < IN_DIM / BKF; ++kt) {
        float4 ax[2][2][2];
        #pragma unroll
        for (int mi = 0; mi < 2; ++mi)
            #pragma unroll
            for (int ks = 0; ks < 2; ++ks) {
                const float* p = &x[(size_t)(row0 + w * 32 + mi * 16 + l16) * IN_DIM
                                    + kt * BKF + ks * 32 + lquad * 8];
                ax[mi][ks][0] = *(const float4*)(p);
                ax[mi][ks][1] = *(const float4*)(p + 4);
            }
        float4 wrow[4];
        #pragma unroll
        for (int r = 0; r < 4; ++r)
            wrow[r] = *(const float4*)(&W[(size_t)(kt * BKF + k0 + r) * NCOL + col0 + n0]);
        #pragma unroll
        for (int c = 0; c < 4; ++c) {
            const float f0 = ((const float*)&wrow[0])[c];
            const float f1 = ((const float*)&wrow[1])[c];
            const float f2 = ((const float*)&wrow[2])[c];
            const float f3 = ((const float*)&wrow[3])[c];
            uint2 hv2, lv2;
            hv2.x = pack_hi(f0, f1); hv2.y = pack_hi(f2, f3);
            lv2.x = pack_hi(f0 - hi_part(f0), f1 - hi_part(f1));
            lv2.y = pack_hi(f2 - hi_part(f2), f3 - hi_part(f3));
            const int off = swz(n0 + c, (n0 + c) * (BKF * 2) + k0 * 2);
            *(uint2*)(sB_hi + off) = hv2;
            *(uint2*)(sB_lo + off) = lv2;
        }
        __syncthreads();
        #pragma unroll
        for (int ks = 0; ks < 2; ++ks) {
            bf16x8 aH[2], aL[2];
            #pragma unroll
            for (int mi = 0; mi < 2; ++mi) {
                uint4 h, l;
                split8((const float*)&ax[mi][ks][0], h, l);
                aH[mi] = __builtin_bit_cast(bf16x8, h);
                aL[mi] = __builtin_bit_cast(bf16x8, l);
            }
            const int kb = ks * 64 + lquad * 16;
            bf16x8 bH[4], bL[4];
            #pragma unroll
            for (int ni = 0; ni < 4; ++ni) {
                const int row = ni * 16 + l16;
                bH[ni] = *(const bf16x8*)(sB_hi + swz(row, row * (BKF * 2) + kb));
            }
            #pragma unroll
            for (int mi = 0; mi < 2; ++mi)
                #pragma unroll
                for (int ni = 0; ni < 4; ++ni)
                    acc[mi][ni] = __builtin_amdgcn_mfma_f32_16x16x32_bf16(bH[ni], aH[mi], acc[mi][ni], 0, 0, 0);
            #pragma unroll
            for (int mi = 0; mi < 2; ++mi)
                #pragma unroll
                for (int ni = 0; ni < 4; ++ni)
                    acc[mi][ni] = __builtin_amdgcn_mfma_f32_16x16x32_bf16(bH[ni], aL[mi], acc[mi][ni], 0, 0, 0);
            #pragma unroll
            for (int ni = 0; ni < 4; ++ni) {
                const int row = ni * 16 + l16;
                bL[ni] = *(const bf16x8*)(sB_lo + swz(row, row * (BKF * 2) + kb));
            }
            #pragma unroll
            for (int mi = 0; mi < 2; ++mi)
                #pragma unroll
                for (int ni = 0; ni < 4; ++ni)
                    acc[mi][ni] = __builtin_amdgcn_mfma_f32_16x16x32_bf16(bL[ni], aH[mi], acc[mi][ni], 0, 0, 0);
        }
        __syncthreads();
    }
    #pragma unroll
    for (int mi = 0; mi < 2; ++mi) {
        const int b = row0 + w * 32 + mi * 16 + l16;
        #pragma unroll
        for (int ni = 0; ni < 4; ++ni) {
            const int n = col0 + ni * 16 + lquad * 4;
            const float4 hv = *(const float4*)(&hq[(size_t)b * NCOL + n]);
            float4 ov;
            ov.x = tanh_fast(__builtin_fmaf(0.9f, hv.x, acc[mi][ni][0]));
            ov.y = tanh_fast(__builtin_fmaf(0.9f, hv.y, acc[mi][ni][1]));
            ov.z = tanh_fast(__builtin_fmaf(0.9f, hv.z, acc[mi][ni][2]));
            ov.w = tanh_fast(__builtin_fmaf(0.9f, hv.w, acc[mi][ni][3]));
            *(float4*)(&out_new[(size_t)b * NCOL + n]) = ov;
            float s = (ov.x + ov.y) + (ov.z + ov.w);
            s += __shfl_xor(s, 16);
            s += __shfl_xor(s, 32);
            if (lquad == 0)
                out_mean[(size_t)b * HID + (col0 >> 4) + ni] = s * 0.0625f;
        }
    }
}

extern "C" void kernel_launch(void* const* d_in, const int* in_sizes, int n_in,
                              void* d_out, int out_size, void* d_ws, size_t ws_size,
                              hipStream_t stream) {
    const float* x  = (const float*)d_in[0];   // [4096, 256]
    const float* hq = (const float*)d_in[1];   // [4096, 512, 16]
    const float* W  = (const float*)d_in[2];   // [256, 512, 16]

    float* out_mean = (float*)d_out;                          // [4096, 512]
    float* out_new  = (float*)d_out + (size_t)BATCH * HID;    // [4096, 512, 16]

    if (ws_size >= WS_NEED) {
        ushort* whi = (ushort*)d_ws;
        ushort* wlo = whi + W_ELEMS;
        prep_w_kernel<<<dim3(NCOL / 256, IN_DIM / 8), 256, 0, stream>>>(W, whi, wlo);
        mqc_main_kernel<<<dim3(BATCH * NCOL / (BM * BN)), 256, 0, stream>>>(
            x, whi, wlo, hq, out_mean, out_new);
    } else {
        mqc_fallback_kernel<<<dim3(BATCH / BM, NCOL / BN), 256, 0, stream>>>(
            x, hq, W, out_mean, out_new);
    }
}

// Round 16
// 90.742 us; speedup vs baseline: 1.1590x; 1.1590x over previous
//
#include <hip/hip_runtime.h>

// Problem dims (fixed by reference)
#define BATCH  4096
#define IN_DIM 256
#define HID    512
#define NCOL   8192            // HID * STATES

// Main tiling: 128x64 block tile, 4 waves stacked on M (32 rows each)
#define BM 128
#define BN 64

typedef __attribute__((ext_vector_type(8))) short bf16x8;
typedef __attribute__((ext_vector_type(4))) float f32x4;
typedef __attribute__((ext_vector_type(4))) float fvec4;   // clang-native, nt-compatible

typedef __attribute__((address_space(1))) const unsigned as1_uint;
typedef __attribute__((address_space(3))) unsigned       as3_uint;

// pack bf16(f0) into low16, bf16(f1) into high16 (truncation) — 1 v_perm_b32
__device__ __forceinline__ uint pack_hi(float f0, float f1) {
    return __builtin_amdgcn_perm(__builtin_bit_cast(uint, f1),
                                 __builtin_bit_cast(uint, f0), 0x07060302u);
}
__device__ __forceinline__ float hi_part(float f) {
    return __builtin_bit_cast(float, __builtin_bit_cast(uint, f) & 0xFFFF0000u);
}
__device__ __forceinline__ float tanh_fast(float x) {
    float e = __builtin_amdgcn_exp2f(x * 2.8853900817779268f); // 2*log2(e)
    float r = __builtin_amdgcn_rcpf(e + 1.0f);
    return __builtin_fmaf(-2.0f, r, 1.0f);
}
// split f[0..7] (k-consecutive) into hi/lo bf16x8 fragments
__device__ __forceinline__ void split8(const float* f, uint4& h, uint4& l) {
    h.x = pack_hi(f[0], f[1]); h.y = pack_hi(f[2], f[3]);
    h.z = pack_hi(f[4], f[5]); h.w = pack_hi(f[6], f[7]);
    l.x = pack_hi(f[0] - hi_part(f[0]), f[1] - hi_part(f[1]));
    l.y = pack_hi(f[2] - hi_part(f[2]), f[3] - hi_part(f[3]));
    l.z = pack_hi(f[4] - hi_part(f[4]), f[5] - hi_part(f[5]));
    l.w = pack_hi(f[6] - hi_part(f[6]), f[7] - hi_part(f[7]));
}

// Workspace layout (ushort elements):
//  whi [0, 2097152)  wlo [2097152, 4194304)   - 8192n x 256k, tiled
//  xhi [4194304, 5242880) xlo [5242880, 6291456) - 4096b x 256k, tiled
// tile layout: plane[((row>>4)*32 + koct)*128 + (row&15)*8 + j], k = koct*8+j
#define W_ELEMS  2097152
#define X_ELEMS  1048576
#define WS_NEED  (12u * 1024u * 1024u)

// ---- prep W: [k][n] f32 -> fragment-ready tiled bf16 hi/lo ----
__global__ __launch_bounds__(256) void prep_w_kernel(
    const float* __restrict__ W, ushort* __restrict__ whi, ushort* __restrict__ wlo)
{
    const int n    = blockIdx.x * 256 + threadIdx.x;   // 0..8191
    const int koct = blockIdx.y;                       // 0..31
    float f[8];
    #pragma unroll
    for (int j = 0; j < 8; ++j)
        f[j] = __builtin_nontemporal_load(&W[(size_t)(koct * 8 + j) * NCOL + n]);
    uint4 h, l;
    split8(f, h, l);
    const size_t o = ((size_t)((n >> 4) * 32 + koct) * 16 + (n & 15)) * 8;
    *(uint4*)(whi + o) = h;
    *(uint4*)(wlo + o) = l;
}

// ---- prep x: [b][k] f32 -> fragment-ready tiled bf16 hi/lo ----
// (r15 proved folding this into the main kernel regresses: the f32+split8
// chain makes the allocator sink the A-prefetch, VGPR 84->52, bench +12us.)
__global__ __launch_bounds__(256) void prep_x_kernel(
    const float* __restrict__ x, ushort* __restrict__ xhi, ushort* __restrict__ xlo)
{
    const int b    = blockIdx.x * 256 + threadIdx.x;   // 0..4095
    const int koct = blockIdx.y;                       // 0..31
    float f[8];
    fvec4 v0 = __builtin_nontemporal_load((const fvec4*)&x[(size_t)b * IN_DIM + koct * 8]);
    fvec4 v1 = __builtin_nontemporal_load((const fvec4*)&x[(size_t)b * IN_DIM + koct * 8 + 4]);
    f[0] = v0.x; f[1] = v0.y; f[2] = v0.z; f[3] = v0.w;
    f[4] = v1.x; f[5] = v1.y; f[6] = v1.z; f[7] = v1.w;
    uint4 h, l;
    split8(f, h, l);
    const size_t o = ((size_t)((b >> 4) * 32 + koct) * 16 + (b & 15)) * 8;
    *(uint4*)(xhi + o) = h;
    *(uint4*)(xlo + o) = l;
}

// ---- main: r11 93-us body + 4-stage double-buffered LDS pipeline ----
// B staged in 8-koct (16KB) sub-chunks, 2 LDS buffers (32KB total, same as
// before): STAGE(next) issues BEFORE KSTEP2(cur), so DMA latency hides under
// 96 MFMAs; only the first barrier pays an exposed DMA wait.
// __launch_bounds__(256,3): cap ~170 regs. r13: (256,4) regressed the bench.
// r4: (256,8) spills. r12: dual-tile accumulators spill. r15: in-kernel x
// conversion kills the prefetch. out_mean store CACHED (r8: nt 4B scalars =
// 8-16x write amp). hq loads CACHED. out_new store nt (r11/r13 A/B: nt wins).
__global__ __launch_bounds__(256, 3) void mqc_main_kernel(
    const ushort* __restrict__ xhi, const ushort* __restrict__ xlo,
    const ushort* __restrict__ whi, const ushort* __restrict__ wlo,
    const float* __restrict__ hq,
    float* __restrict__ out_mean, float* __restrict__ out_new)
{
    // 2 buffers x (4 ntiles x 8 kl x 16 l16 x 8) per plane = 2 x 8 KB per plane
    __shared__ ushort sBh[8192], sBl[8192];    // 16 KiB + 16 KiB

    const int t     = threadIdx.x;
    const int lane  = t & 63;
    const int w     = t >> 6;           // wave 0..3 -> rows w*32..w*32+31
    const int lquad = lane >> 4;        // 0..3
    const int l16   = lane & 15;

    // XCD-clustered bijective block mapping (4096 = 8 xcd * 4 rowg * 128 colg)
    const int wgid = blockIdx.x;
    const int xcd  = wgid & 7;
    const int q    = wgid >> 3;
    const int rowg = (xcd << 2) | (q & 3);   // 0..31
    const int colg = q >> 2;                 // 0..127
    const int row0 = rowg * BM;
    const int col0 = colg * BN;
    const int btile0 = (row0 >> 4) + w * 2;
    const int ntile0 = col0 >> 4;

    f32x4 acc[2][4] = {};               // [mi][ni]; D[n][b]: row=n, col=b

    // Stage one 8-koct sub-chunk of B (16 KB) into buffer BUF via DMA w16.
    // c = itc*4 + w in 0..15: plane=c>>3, nt=(c>>1)&3, kslot=c&1,
    // kl = kslot*4 + lane>>4 (0..7). dst = BUF*4096 + nt*1024 + kl*128 + l16*8.
    #define STAGE(BUF, KOCT0) {                                                     \
        _Pragma("unroll")                                                           \
        for (int itc = 0; itc < 4; ++itc) {                                         \
            const int c  = itc * 4 + w;                                             \
            const int nt = (c >> 1) & 3;                                            \
            const int kl = (c & 1) * 4 + (lane >> 4);                               \
            const ushort* srcp = ((c >> 3) ? wlo : whi)                             \
                + ((size_t)(ntile0 + nt) * 32 + (KOCT0) + kl) * 128 + (lane & 15) * 8; \
            ushort* dstp = ((c >> 3) ? sBl : sBh) + (BUF) * 4096 + nt * 1024        \
                           + (c & 1) * 512;                                         \
            __builtin_amdgcn_global_load_lds((as1_uint*)srcp, (as3_uint*)dstp,      \
                                             16, 0, 0);                             \
        }                                                                           \
    }

    // prefetch A fragments for the 2 k-steps of sub-chunk at KOCT0 into regs
    #define APREF(AH, AL, KOCT0) {                                                  \
        _Pragma("unroll")                                                           \
        for (int s = 0; s < 2; ++s) {                                               \
            const int koct = (KOCT0) + s * 4 + lquad;                               \
            _Pragma("unroll")                                                       \
            for (int mi = 0; mi < 2; ++mi) {                                        \
                const size_t o = ((size_t)(btile0 + mi) * 32 + koct) * 128 + l16 * 8; \
                AH[s][mi] = *(const bf16x8*)(xhi + o);                              \
                AL[s][mi] = *(const bf16x8*)(xlo + o);                              \
            }                                                                       \
        }                                                                           \
    }

    // 2 MFMA k-steps over buffer BUF using prefetched A regs
    #define KSTEP2(BUF, AH, AL) {                                                   \
        _Pragma("unroll")                                                           \
        for (int s = 0; s < 2; ++s) {                                               \
            const int bidx = (BUF) * 4096 + (s * 4 + lquad) * 128 + l16 * 8;        \
            bf16x8 bH[4], bL[4];                                                    \
            _Pragma("unroll")                                                       \
            for (int ni = 0; ni < 4; ++ni) {                                        \
                bH[ni] = *(const bf16x8*)(sBh + ni * 1024 + bidx);                  \
                bL[ni] = *(const bf16x8*)(sBl + ni * 1024 + bidx);                  \
            }                                                                       \
            _Pragma("unroll")                                                       \
            for (int mi = 0; mi < 2; ++mi)                                          \
                _Pragma("unroll")                                                   \
                for (int ni = 0; ni < 4; ++ni)                                      \
                    acc[mi][ni] = __builtin_amdgcn_mfma_f32_16x16x32_bf16(bH[ni], AH[s][mi], acc[mi][ni], 0, 0, 0); \
            _Pragma("unroll")                                                       \
            for (int mi = 0; mi < 2; ++mi)                                          \
                _Pragma("unroll")                                                   \
                for (int ni = 0; ni < 4; ++ni)                                      \
                    acc[mi][ni] = __builtin_amdgcn_mfma_f32_16x16x32_bf16(bH[ni], AL[s][mi], acc[mi][ni], 0, 0, 0); \
            _Pragma("unroll")                                                       \
            for (int mi = 0; mi < 2; ++mi)                                          \
                _Pragma("unroll")                                                   \
                for (int ni = 0; ni < 4; ++ni)                                      \
                    acc[mi][ni] = __builtin_amdgcn_mfma_f32_16x16x32_bf16(bL[ni], AH[s][mi], acc[mi][ni], 0, 0, 0); \
        }                                                                           \
    }

    bf16x8 AaH[2][2], AaL[2][2], AbH[2][2], AbL[2][2];
    fvec4 hv[2][4];

    // 4 sub-chunks of 8 koct: 0, 8, 16, 24. Double-buffered pipeline.
    STAGE(0, 0);  APREF(AaH, AaL, 0);
    __syncthreads();                        // sub-chunk 0 ready (exposed wait)
    STAGE(1, 8);  APREF(AbH, AbL, 8);       // next stage in flight...
    KSTEP2(0, AaH, AaL);                    // ...hides under compute of cur
    __syncthreads();                        // sub-chunk 1 ready (covered)
    STAGE(0, 16); APREF(AaH, AaL, 16);
    KSTEP2(1, AbH, AbL);
    __syncthreads();                        // sub-chunk 2 ready (covered)
    STAGE(1, 24); APREF(AbH, AbL, 24);
    // epilogue hq prefetch (cached): covered by the next 96 MFMAs
    #pragma unroll
    for (int mi = 0; mi < 2; ++mi) {
        const int b = row0 + w * 32 + mi * 16 + l16;
        #pragma unroll
        for (int ni = 0; ni < 4; ++ni) {
            const int n = col0 + ni * 16 + lquad * 4;
            hv[mi][ni] = *(const fvec4*)&hq[(size_t)b * NCOL + n];
        }
    }
    KSTEP2(0, AaH, AaL);
    __syncthreads();                        // sub-chunk 3 ready (covered)
    KSTEP2(1, AbH, AbL);
    #undef STAGE
    #undef APREF
    #undef KSTEP2

    // ---- fused epilogue: tanh(C + 0.9*h), nt out_new store, cached out_mean.
    //      D[n][b]: n = col0+ni*16+4*lquad+reg, b = row0+w*32+mi*16+l16
    #pragma unroll
    for (int mi = 0; mi < 2; ++mi) {
        const int b = row0 + w * 32 + mi * 16 + l16;
        #pragma unroll
        for (int ni = 0; ni < 4; ++ni) {
            const int n = col0 + ni * 16 + lquad * 4;
            fvec4 ov;
            ov.x = tanh_fast(__builtin_fmaf(0.9f, hv[mi][ni].x, acc[mi][ni][0]));
            ov.y = tanh_fast(__builtin_fmaf(0.9f, hv[mi][ni].y, acc[mi][ni][1]));
            ov.z = tanh_fast(__builtin_fmaf(0.9f, hv[mi][ni].z, acc[mi][ni][2]));
            ov.w = tanh_fast(__builtin_fmaf(0.9f, hv[mi][ni].w, acc[mi][ni][3]));
            __builtin_nontemporal_store(ov, (fvec4*)&out_new[(size_t)b * NCOL + n]);
            float s = (ov.x + ov.y) + (ov.z + ov.w);
            s += __shfl_xor(s, 16);
            s += __shfl_xor(s, 32);
            if (lquad == 0)
                out_mean[(size_t)b * HID + (col0 >> 4) + ni] = s * 0.0625f;
        }
    }
}

// ================= fallback (round-5 proven kernel, used if ws too small) ======
#define BKF 64
__device__ __forceinline__ int swz(int row, int byteoff) {
    return byteoff ^ ((((row & 7) ^ ((row >> 3) & 7))) << 4);
}
__global__ __launch_bounds__(256, 4) void mqc_fallback_kernel(
    const float* __restrict__ x, const float* __restrict__ hq,
    const float* __restrict__ W,
    float* __restrict__ out_mean, float* __restrict__ out_new)
{
    __shared__ char sB[2 * BN * BKF * 2];
    char* const sB_hi = sB;
    char* const sB_lo = sB + BN * BKF * 2;
    const int t = threadIdx.x, lane = t & 63, w = t >> 6;
    const int lquad = lane >> 4, l16 = lane & 15;
    const int row0 = blockIdx.x * BM, col0 = blockIdx.y * BN;
    const int k0 = (t >> 4) * 4, n0 = (t & 15) * 4;
    f32x4 acc[2][4] = {};
    for (int kt = 0; kt < IN_DIM / BKF; ++kt) {
        float4 ax[2][2][2];
        #pragma unroll
        for (int mi = 0; mi < 2; ++mi)
            #pragma unroll
            for (int ks = 0; ks < 2; ++ks) {
                const float* p = &x[(size_t)(row0 + w * 32 + mi * 16 + l16) * IN_DIM
                                    + kt * BKF + ks * 32 + lquad * 8];
                ax[mi][ks][0] = *(const float4*)(p);
                ax[mi][ks][1] = *(const float4*)(p + 4);
            }
        float4 wrow[4];
        #pragma unroll
        for (int r = 0; r < 4; ++r)
            wrow[r] = *(const float4*)(&W[(size_t)(kt * BKF + k0 + r) * NCOL + col0 + n0]);
        #pragma unroll
        for (int c = 0; c < 4; ++c) {
            const float f0 = ((const float*)&wrow[0])[c];
            const float f1 = ((const float*)&wrow[1])[c];
            const float f2 = ((const float*)&wrow[2])[c];
            const float f3 = ((const float*)&wrow[3])[c];
            uint2 hv2, lv2;
            hv2.x = pack_hi(f0, f1); hv2.y = pack_hi(f2, f3);
            lv2.x = pack_hi(f0 - hi_part(f0), f1 - hi_part(f1));
            lv2.y = pack_hi(f2 - hi_part(f2), f3 - hi_part(f3));
            const int off = swz(n0 + c, (n0 + c) * (BKF * 2) + k0 * 2);
            *(uint2*)(sB_hi + off) = hv2;
            *(uint2*)(sB_lo + off) = lv2;
        }
        __syncthreads();
        #pragma unroll
        for (int ks = 0; ks < 2; ++ks) {
            bf16x8 aH[2], aL[2];
            #pragma unroll
            for (int mi = 0; mi < 2; ++mi) {
                uint4 h, l;
                split8((const float*)&ax[mi][ks][0], h, l);
                aH[mi] = __builtin_bit_cast(bf16x8, h);
                aL[mi] = __builtin_bit_cast(bf16x8, l);
            }
            const int kb = ks * 64 + lquad * 16;
            bf16x8 bH[4], bL[4];
            #pragma unroll
            for (int ni = 0; ni < 4; ++ni) {
                const int row = ni * 16 + l16;
                bH[ni] = *(const bf16x8*)(sB_hi + swz(row, row * (BKF * 2) + kb));
            }
            #pragma unroll
            for (int mi = 0; mi < 2; ++mi)
                #pragma unroll
                for (int ni = 0; ni < 4; ++ni)
                    acc[mi][ni] = __builtin_amdgcn_mfma_f32_16x16x32_bf16(bH[ni], aH[mi], acc[mi][ni], 0, 0, 0);
            #pragma unroll
            for (int mi = 0; mi < 2; ++mi)
                #pragma unroll
                for (int ni = 0; ni < 4; ++ni)
                    acc[mi][ni] = __builtin_amdgcn_mfma_f32_16x16x32_bf16(bH[ni], aL[mi], acc[mi][ni], 0, 0, 0);
            #pragma unroll
            for (int ni = 0; ni < 4; ++ni) {
                const int row = ni * 16 + l16;
                bL[ni] = *(const bf16x8*)(sB_lo + swz(row, row * (BKF * 2) + kb));
            }
            #pragma unroll
            for (int mi = 0; mi < 2; ++mi)
                #pragma unroll
                for (int ni = 0; ni < 4; ++ni)
                    acc[mi][ni] = __builtin_amdgcn_mfma_f32_16x16x32_bf16(bL[ni], aH[mi], acc[mi][ni], 0, 0, 0);
        }
        __syncthreads();
    }
    #pragma unroll
    for (int mi = 0; mi < 2; ++mi) {
        const int b = row0 + w * 32 + mi * 16 + l16;
        #pragma unroll
        for (int ni = 0; ni < 4; ++ni) {
            const int n = col0 + ni * 16 + lquad * 4;
            const float4 hv = *(const float4*)(&hq[(size_t)b * NCOL + n]);
            float4 ov;
            ov.x = tanh_fast(__builtin_fmaf(0.9f, hv.x, acc[mi][ni][0]));
            ov.y = tanh_fast(__builtin_fmaf(0.9f, hv.y, acc[mi][ni][1]));
            ov.z = tanh_fast(__builtin_fmaf(0.9f, hv.z, acc[mi][ni][2]));
            ov.w = tanh_fast(__builtin_fmaf(0.9f, hv.w, acc[mi][ni][3]));
            *(float4*)(&out_new[(size_t)b * NCOL + n]) = ov;
            float s = (ov.x + ov.y) + (ov.z + ov.w);
            s += __shfl_xor(s, 16);
            s += __shfl_xor(s, 32);
            if (lquad == 0)
                out_mean[(size_t)b * HID + (col0 >> 4) + ni] = s * 0.0625f;
        }
    }
}

extern "C" void kernel_launch(void* const* d_in, const int* in_sizes, int n_in,
                              void* d_out, int out_size, void* d_ws, size_t ws_size,
                              hipStream_t stream) {
    const float* x  = (const float*)d_in[0];   // [4096, 256]
    const float* hq = (const float*)d_in[1];   // [4096, 512, 16]
    const float* W  = (const float*)d_in[2];   // [256, 512, 16]

    float* out_mean = (float*)d_out;                          // [4096, 512]
    float* out_new  = (float*)d_out + (size_t)BATCH * HID;    // [4096, 512, 16]

    if (ws_size >= WS_NEED) {
        ushort* whi = (ushort*)d_ws;
        ushort* wlo = whi + W_ELEMS;
        ushort* xhi = wlo + W_ELEMS;
        ushort* xlo = xhi + X_ELEMS;
        prep_w_kernel<<<dim3(NCOL / 256, IN_DIM / 8), 256, 0, stream>>>(W, whi, wlo);
        prep_x_kernel<<<dim3(BATCH / 256, IN_DIM / 8), 256, 0, stream>>>(x, xhi, xlo);
        mqc_main_kernel<<<dim3(BATCH * NCOL / (BM * BN)), 256, 0, stream>>>(
            xhi, xlo, whi, wlo, hq, out_mean, out_new);
    } else {
        mqc_fallback_kernel<<<dim3(BATCH / BM, NCOL / BN), 256, 0, stream>>>(
            x, hq, W, out_mean, out_new);
    }
}

// Round 17
// 90.546 us; speedup vs baseline: 1.1615x; 1.0022x over previous
//
#include <hip/hip_runtime.h>

// Problem dims (fixed by reference)
#define BATCH  4096
#define IN_DIM 256
#define HID    512
#define NCOL   8192            // HID * STATES

// Main tiling: 128x64 block tile, 4 waves stacked on M (32 rows each)
#define BM 128
#define BN 64

typedef __attribute__((ext_vector_type(8))) short bf16x8;
typedef __attribute__((ext_vector_type(4))) float f32x4;
typedef __attribute__((ext_vector_type(4))) float fvec4;   // clang-native, nt-compatible

typedef __attribute__((address_space(1))) const unsigned as1_uint;
typedef __attribute__((address_space(3))) unsigned       as3_uint;

// pack bf16(f0) into low16, bf16(f1) into high16 (truncation) — 1 v_perm_b32
__device__ __forceinline__ uint pack_hi(float f0, float f1) {
    return __builtin_amdgcn_perm(__builtin_bit_cast(uint, f1),
                                 __builtin_bit_cast(uint, f0), 0x07060302u);
}
__device__ __forceinline__ float hi_part(float f) {
    return __builtin_bit_cast(float, __builtin_bit_cast(uint, f) & 0xFFFF0000u);
}
__device__ __forceinline__ float tanh_fast(float x) {
    float e = __builtin_amdgcn_exp2f(x * 2.8853900817779268f); // 2*log2(e)
    float r = __builtin_amdgcn_rcpf(e + 1.0f);
    return __builtin_fmaf(-2.0f, r, 1.0f);
}
// split f[0..7] (k-consecutive) into hi/lo bf16x8 fragments
__device__ __forceinline__ void split8(const float* f, uint4& h, uint4& l) {
    h.x = pack_hi(f[0], f[1]); h.y = pack_hi(f[2], f[3]);
    h.z = pack_hi(f[4], f[5]); h.w = pack_hi(f[6], f[7]);
    l.x = pack_hi(f[0] - hi_part(f[0]), f[1] - hi_part(f[1]));
    l.y = pack_hi(f[2] - hi_part(f[2]), f[3] - hi_part(f[3]));
    l.z = pack_hi(f[4] - hi_part(f[4]), f[5] - hi_part(f[5]));
    l.w = pack_hi(f[6] - hi_part(f[6]), f[7] - hi_part(f[7]));
}

// Workspace layout (ushort elements):
//  whi [0, 2097152)  wlo [2097152, 4194304)   - 8192n x 256k, tiled
//  xhi [4194304, 5242880) xlo [5242880, 6291456) - 4096b x 256k, tiled
// tile layout: plane[((row>>4)*32 + koct)*128 + (row&15)*8 + j], k = koct*8+j
#define W_ELEMS  2097152
#define X_ELEMS  1048576
#define WS_NEED  (12u * 1024u * 1024u)

// ---- prep W: [k][n] f32 -> fragment-ready tiled bf16 hi/lo ----
__global__ __launch_bounds__(256) void prep_w_kernel(
    const float* __restrict__ W, ushort* __restrict__ whi, ushort* __restrict__ wlo)
{
    const int n    = blockIdx.x * 256 + threadIdx.x;   // 0..8191
    const int koct = blockIdx.y;                       // 0..31
    float f[8];
    #pragma unroll
    for (int j = 0; j < 8; ++j)
        f[j] = __builtin_nontemporal_load(&W[(size_t)(koct * 8 + j) * NCOL + n]);
    uint4 h, l;
    split8(f, h, l);
    const size_t o = ((size_t)((n >> 4) * 32 + koct) * 16 + (n & 15)) * 8;
    *(uint4*)(whi + o) = h;
    *(uint4*)(wlo + o) = l;
}

// ---- prep x: [b][k] f32 -> fragment-ready tiled bf16 hi/lo ----
// (r15 proved folding this into the main kernel regresses: the f32+split8
// chain makes the allocator sink the A-prefetch, VGPR 84->52, bench +12us.)
__global__ __launch_bounds__(256) void prep_x_kernel(
    const float* __restrict__ x, ushort* __restrict__ xhi, ushort* __restrict__ xlo)
{
    const int b    = blockIdx.x * 256 + threadIdx.x;   // 0..4095
    const int koct = blockIdx.y;                       // 0..31
    float f[8];
    fvec4 v0 = __builtin_nontemporal_load((const fvec4*)&x[(size_t)b * IN_DIM + koct * 8]);
    fvec4 v1 = __builtin_nontemporal_load((const fvec4*)&x[(size_t)b * IN_DIM + koct * 8 + 4]);
    f[0] = v0.x; f[1] = v0.y; f[2] = v0.z; f[3] = v0.w;
    f[4] = v1.x; f[5] = v1.y; f[6] = v1.z; f[7] = v1.w;
    uint4 h, l;
    split8(f, h, l);
    const size_t o = ((size_t)((b >> 4) * 32 + koct) * 16 + (b & 15)) * 8;
    *(uint4*)(xhi + o) = h;
    *(uint4*)(xlo + o) = l;
}

// ---- main: r16 pipelined body, single-variable A/B: bound (256,3)->(256,4) ----
// Unified reg demand measured r16: 64 VGPR + 32 acc AGPR = 96 <= 128 cap, so
// (256,4) should hold the ping-pong AND admit 4 blocks/CU (LDS 32KB*4=128KB).
// r13's bench regression under (256,4) traced to the simultaneous nt->cached
// store swap, not the bound (its main-kernel rocprof dur IMPROVED 118->107).
// Tripwires: VGPR_Count <= 52 => allocator sank prefetches, revert to (256,3);
// hbm_bytes > 3.3e8 => spills, same. r4: (256,8) catastrophic. r12: dual-tile
// accumulators spill. r15: in-kernel x conversion kills the prefetch.
// out_mean store CACHED (r8: nt 4B scalars = 8-16x write amp). hq loads
// CACHED. out_new store nt (r11/r13 A/B: nt wins the bench).
__global__ __launch_bounds__(256, 4) void mqc_main_kernel(
    const ushort* __restrict__ xhi, const ushort* __restrict__ xlo,
    const ushort* __restrict__ whi, const ushort* __restrict__ wlo,
    const float* __restrict__ hq,
    float* __restrict__ out_mean, float* __restrict__ out_new)
{
    // 2 buffers x (4 ntiles x 8 kl x 16 l16 x 8) per plane = 2 x 8 KB per plane
    __shared__ ushort sBh[8192], sBl[8192];    // 16 KiB + 16 KiB

    const int t     = threadIdx.x;
    const int lane  = t & 63;
    const int w     = t >> 6;           // wave 0..3 -> rows w*32..w*32+31
    const int lquad = lane >> 4;        // 0..3
    const int l16   = lane & 15;

    // XCD-clustered bijective block mapping (4096 = 8 xcd * 4 rowg * 128 colg)
    const int wgid = blockIdx.x;
    const int xcd  = wgid & 7;
    const int q    = wgid >> 3;
    const int rowg = (xcd << 2) | (q & 3);   // 0..31
    const int colg = q >> 2;                 // 0..127
    const int row0 = rowg * BM;
    const int col0 = colg * BN;
    const int btile0 = (row0 >> 4) + w * 2;
    const int ntile0 = col0 >> 4;

    f32x4 acc[2][4] = {};               // [mi][ni]; D[n][b]: row=n, col=b

    // Stage one 8-koct sub-chunk of B (16 KB) into buffer BUF via DMA w16.
    // c = itc*4 + w in 0..15: plane=c>>3, nt=(c>>1)&3, kslot=c&1,
    // kl = kslot*4 + lane>>4 (0..7). dst = BUF*4096 + nt*1024 + kl*128 + l16*8.
    #define STAGE(BUF, KOCT0) {                                                     \
        _Pragma("unroll")                                                           \
        for (int itc = 0; itc < 4; ++itc) {                                         \
            const int c  = itc * 4 + w;                                             \
            const int nt = (c >> 1) & 3;                                            \
            const int kl = (c & 1) * 4 + (lane >> 4);                               \
            const ushort* srcp = ((c >> 3) ? wlo : whi)                             \
                + ((size_t)(ntile0 + nt) * 32 + (KOCT0) + kl) * 128 + (lane & 15) * 8; \
            ushort* dstp = ((c >> 3) ? sBl : sBh) + (BUF) * 4096 + nt * 1024        \
                           + (c & 1) * 512;                                         \
            __builtin_amdgcn_global_load_lds((as1_uint*)srcp, (as3_uint*)dstp,      \
                                             16, 0, 0);                             \
        }                                                                           \
    }

    // prefetch A fragments for the 2 k-steps of sub-chunk at KOCT0 into regs
    #define APREF(AH, AL, KOCT0) {                                                  \
        _Pragma("unroll")                                                           \
        for (int s = 0; s < 2; ++s) {                                               \
            const int koct = (KOCT0) + s * 4 + lquad;                               \
            _Pragma("unroll")                                                       \
            for (int mi = 0; mi < 2; ++mi) {                                        \
                const size_t o = ((size_t)(btile0 + mi) * 32 + koct) * 128 + l16 * 8; \
                AH[s][mi] = *(const bf16x8*)(xhi + o);                              \
                AL[s][mi] = *(const bf16x8*)(xlo + o);                              \
            }                                                                       \
        }                                                                           \
    }

    // 2 MFMA k-steps over buffer BUF using prefetched A regs
    #define KSTEP2(BUF, AH, AL) {                                                   \
        _Pragma("unroll")                                                           \
        for (int s = 0; s < 2; ++s) {                                               \
            const int bidx = (BUF) * 4096 + (s * 4 + lquad) * 128 + l16 * 8;        \
            bf16x8 bH[4], bL[4];                                                    \
            _Pragma("unroll")                                                       \
            for (int ni = 0; ni < 4; ++ni) {                                        \
                bH[ni] = *(const bf16x8*)(sBh + ni * 1024 + bidx);                  \
                bL[ni] = *(const bf16x8*)(sBl + ni * 1024 + bidx);                  \
            }                                                                       \
            _Pragma("unroll")                                                       \
            for (int mi = 0; mi < 2; ++mi)                                          \
                _Pragma("unroll")                                                   \
                for (int ni = 0; ni < 4; ++ni)                                      \
                    acc[mi][ni] = __builtin_amdgcn_mfma_f32_16x16x32_bf16(bH[ni], AH[s][mi], acc[mi][ni], 0, 0, 0); \
            _Pragma("unroll")                                                       \
            for (int mi = 0; mi < 2; ++mi)                                          \
                _Pragma("unroll")                                                   \
                for (int ni = 0; ni < 4; ++ni)                                      \
                    acc[mi][ni] = __builtin_amdgcn_mfma_f32_16x16x32_bf16(bH[ni], AL[s][mi], acc[mi][ni], 0, 0, 0); \
            _Pragma("unroll")                                                       \
            for (int mi = 0; mi < 2; ++mi)                                          \
                _Pragma("unroll")                                                   \
                for (int ni = 0; ni < 4; ++ni)                                      \
                    acc[mi][ni] = __builtin_amdgcn_mfma_f32_16x16x32_bf16(bL[ni], AH[s][mi], acc[mi][ni], 0, 0, 0); \
        }                                                                           \
    }

    bf16x8 AaH[2][2], AaL[2][2], AbH[2][2], AbL[2][2];
    fvec4 hv[2][4];

    // 4 sub-chunks of 8 koct: 0, 8, 16, 24. Double-buffered pipeline.
    STAGE(0, 0);  APREF(AaH, AaL, 0);
    __syncthreads();                        // sub-chunk 0 ready (exposed wait)
    STAGE(1, 8);  APREF(AbH, AbL, 8);       // next stage in flight...
    KSTEP2(0, AaH, AaL);                    // ...hides under compute of cur
    __syncthreads();                        // sub-chunk 1 ready (covered)
    STAGE(0, 16); APREF(AaH, AaL, 16);
    KSTEP2(1, AbH, AbL);
    __syncthreads();                        // sub-chunk 2 ready (covered)
    STAGE(1, 24); APREF(AbH, AbL, 24);
    // epilogue hq prefetch (cached): covered by the next 96 MFMAs
    #pragma unroll
    for (int mi = 0; mi < 2; ++mi) {
        const int b = row0 + w * 32 + mi * 16 + l16;
        #pragma unroll
        for (int ni = 0; ni < 4; ++ni) {
            const int n = col0 + ni * 16 + lquad * 4;
            hv[mi][ni] = *(const fvec4*)&hq[(size_t)b * NCOL + n];
        }
    }
    KSTEP2(0, AaH, AaL);
    __syncthreads();                        // sub-chunk 3 ready (covered)
    KSTEP2(1, AbH, AbL);
    #undef STAGE
    #undef APREF
    #undef KSTEP2

    // ---- fused epilogue: tanh(C + 0.9*h), nt out_new store, cached out_mean.
    //      D[n][b]: n = col0+ni*16+4*lquad+reg, b = row0+w*32+mi*16+l16
    #pragma unroll
    for (int mi = 0; mi < 2; ++mi) {
        const int b = row0 + w * 32 + mi * 16 + l16;
        #pragma unroll
        for (int ni = 0; ni < 4; ++ni) {
            const int n = col0 + ni * 16 + lquad * 4;
            fvec4 ov;
            ov.x = tanh_fast(__builtin_fmaf(0.9f, hv[mi][ni].x, acc[mi][ni][0]));
            ov.y = tanh_fast(__builtin_fmaf(0.9f, hv[mi][ni].y, acc[mi][ni][1]));
            ov.z = tanh_fast(__builtin_fmaf(0.9f, hv[mi][ni].z, acc[mi][ni][2]));
            ov.w = tanh_fast(__builtin_fmaf(0.9f, hv[mi][ni].w, acc[mi][ni][3]));
            __builtin_nontemporal_store(ov, (fvec4*)&out_new[(size_t)b * NCOL + n]);
            float s = (ov.x + ov.y) + (ov.z + ov.w);
            s += __shfl_xor(s, 16);
            s += __shfl_xor(s, 32);
            if (lquad == 0)
                out_mean[(size_t)b * HID + (col0 >> 4) + ni] = s * 0.0625f;
        }
    }
}

// ================= fallback (round-5 proven kernel, used if ws too small) ======
#define BKF 64
__device__ __forceinline__ int swz(int row, int byteoff) {
    return byteoff ^ ((((row & 7) ^ ((row >> 3) & 7))) << 4);
}
__global__ __launch_bounds__(256, 4) void mqc_fallback_kernel(
    const float* __restrict__ x, const float* __restrict__ hq,
    const float* __restrict__ W,
    float* __restrict__ out_mean, float* __restrict__ out_new)
{
    __shared__ char sB[2 * BN * BKF * 2];
    char* const sB_hi = sB;
    char* const sB_lo = sB + BN * BKF * 2;
    const int t = threadIdx.x, lane = t & 63, w = t >> 6;
    const int lquad = lane >> 4, l16 = lane & 15;
    const int row0 = blockIdx.x * BM, col0 = blockIdx.y * BN;
    const int k0 = (t >> 4) * 4, n0 = (t & 15) * 4;
    f32x4 acc[2][4] = {};
    for (int kt = 0; kt < IN_DIM / BKF; ++kt) {
        float4 ax[2][2][2];
        #pragma unroll
        for (int mi = 0; mi < 2; ++mi)
            #pragma unroll
            for (int ks = 0; ks < 2; ++ks) {
                const float* p = &x[(size_t)(row0 + w * 32 + mi * 16 + l16) * IN_DIM
                                    + kt * BKF + ks * 32 + lquad * 8];
                ax[mi][ks][0] = *(const float4*)(p);
                ax[mi][ks][1] = *(const float4*)(p + 4);
            }
        float4 wrow[4];
        #pragma unroll
        for (int r = 0; r < 4; ++r)
            wrow[r] = *(const float4*)(&W[(size_t)(kt * BKF + k0 + r) * NCOL + col0 + n0]);
        #pragma unroll
        for (int c = 0; c < 4; ++c) {
            const float f0 = ((const float*)&wrow[0])[c];
            const float f1 = ((const float*)&wrow[1])[c];
            const float f2 = ((const float*)&wrow[2])[c];
            const float f3 = ((const float*)&wrow[3])[c];
            uint2 hv2, lv2;
            hv2.x = pack_hi(f0, f1); hv2.y = pack_hi(f2, f3);
            lv2.x = pack_hi(f0 - hi_part(f0), f1 - hi_part(f1));
            lv2.y = pack_hi(f2 - hi_part(f2), f3 - hi_part(f3));
            const int off = swz(n0 + c, (n0 + c) * (BKF * 2) + k0 * 2);
            *(uint2*)(sB_hi + off) = hv2;
            *(uint2*)(sB_lo + off) = lv2;
        }
        __syncthreads();
        #pragma unroll
        for (int ks = 0; ks < 2; ++ks) {
            bf16x8 aH[2], aL[2];
            #pragma unroll
            for (int mi = 0; mi < 2; ++mi) {
                uint4 h, l;
                split8((const float*)&ax[mi][ks][0], h, l);
                aH[mi] = __builtin_bit_cast(bf16x8, h);
                aL[mi] = __builtin_bit_cast(bf16x8, l);
            }
            const int kb = ks * 64 + lquad * 16;
            bf16x8 bH[4], bL[4];
            #pragma unroll
            for (int ni = 0; ni < 4; ++ni) {
                const int row = ni * 16 + l16;
                bH[ni] = *(const bf16x8*)(sB_hi + swz(row, row * (BKF * 2) + kb));
            }
            #pragma unroll
            for (int mi = 0; mi < 2; ++mi)
                #pragma unroll
                for (int ni = 0; ni < 4; ++ni)
                    acc[mi][ni] = __builtin_amdgcn_mfma_f32_16x16x32_bf16(bH[ni], aH[mi], acc[mi][ni], 0, 0, 0);
            #pragma unroll
            for (int mi = 0; mi < 2; ++mi)
                #pragma unroll
                for (int ni = 0; ni < 4; ++ni)
                    acc[mi][ni] = __builtin_amdgcn_mfma_f32_16x16x32_bf16(bH[ni], aL[mi], acc[mi][ni], 0, 0, 0);
            #pragma unroll
            for (int ni = 0; ni < 4; ++ni) {
                const int row = ni * 16 + l16;
                bL[ni] = *(const bf16x8*)(sB_lo + swz(row, row * (BKF * 2) + kb));
            }
            #pragma unroll
            for (int mi = 0; mi < 2; ++mi)
                #pragma unroll
                for (int ni = 0; ni < 4; ++ni)
                    acc[mi][ni] = __builtin_amdgcn_mfma_f32_16x16x32_bf16(bL[ni], aH[mi], acc[mi][ni], 0, 0, 0);
        }
        __syncthreads();
    }
    #pragma unroll
    for (int mi = 0; mi < 2; ++mi) {
        const int b = row0 + w * 32 + mi * 16 + l16;
        #pragma unroll
        for (int ni = 0; ni < 4; ++ni) {
            const int n = col0 + ni * 16 + lquad * 4;
            const float4 hv = *(const float4*)(&hq[(size_t)b * NCOL + n]);
            float4 ov;
            ov.x = tanh_fast(__builtin_fmaf(0.9f, hv.x, acc[mi][ni][0]));
            ov.y = tanh_fast(__builtin_fmaf(0.9f, hv.y, acc[mi][ni][1]));
            ov.z = tanh_fast(__builtin_fmaf(0.9f, hv.z, acc[mi][ni][2]));
            ov.w = tanh_fast(__builtin_fmaf(0.9f, hv.w, acc[mi][ni][3]));
            *(float4*)(&out_new[(size_t)b * NCOL + n]) = ov;
            float s = (ov.x + ov.y) + (ov.z + ov.w);
            s += __shfl_xor(s, 16);
            s += __shfl_xor(s, 32);
            if (lquad == 0)
                out_mean[(size_t)b * HID + (col0 >> 4) + ni] = s * 0.0625f;
        }
    }
}

extern "C" void kernel_launch(void* const* d_in, const int* in_sizes, int n_in,
                              void* d_out, int out_size, void* d_ws, size_t ws_size,
                              hipStream_t stream) {
    const float* x  = (const float*)d_in[0];   // [4096, 256]
    const float* hq = (const float*)d_in[1];   // [4096, 512, 16]
    const float* W  = (const float*)d_in[2];   // [256, 512, 16]

    float* out_mean = (float*)d_out;                          // [4096, 512]
    float* out_new  = (float*)d_out + (size_t)BATCH * HID;    // [4096, 512, 16]

    if (ws_size >= WS_NEED) {
        ushort* whi = (ushort*)d_ws;
        ushort* wlo = whi + W_ELEMS;
        ushort* xhi = wlo + W_ELEMS;
        ushort* xlo = xhi + X_ELEMS;
        prep_w_kernel<<<dim3(NCOL / 256, IN_DIM / 8), 256, 0, stream>>>(W, whi, wlo);
        prep_x_kernel<<<dim3(BATCH / 256, IN_DIM / 8), 256, 0, stream>>>(x, xhi, xlo);
        mqc_main_kernel<<<dim3(BATCH * NCOL / (BM * BN)), 256, 0, stream>>>(
            xhi, xlo, whi, wlo, hq, out_mean, out_new);
    } else {
        mqc_fallback_kernel<<<dim3(BATCH / BM, NCOL / BN), 256, 0, stream>>>(
            x, hq, W, out_mean, out_new);
    }
}

// Round 18
// 90.007 us; speedup vs baseline: 1.1684x; 1.0060x over previous
//
#include <hip/hip_runtime.h>

// Problem dims (fixed by reference)
#define BATCH  4096
#define IN_DIM 256
#define HID    512
#define NCOL   8192            // HID * STATES

// Main tiling: 128x64 block tile, 4 waves stacked on M (32 rows each)
#define BM 128
#define BN 64

typedef __attribute__((ext_vector_type(8))) short bf16x8;
typedef __attribute__((ext_vector_type(4))) float f32x4;
typedef __attribute__((ext_vector_type(4))) float fvec4;   // clang-native, nt-compatible

typedef __attribute__((address_space(1))) const unsigned as1_uint;
typedef __attribute__((address_space(3))) unsigned       as3_uint;

// pack bf16(f0) into low16, bf16(f1) into high16 (truncation) — 1 v_perm_b32
__device__ __forceinline__ uint pack_hi(float f0, float f1) {
    return __builtin_amdgcn_perm(__builtin_bit_cast(uint, f1),
                                 __builtin_bit_cast(uint, f0), 0x07060302u);
}
__device__ __forceinline__ float hi_part(float f) {
    return __builtin_bit_cast(float, __builtin_bit_cast(uint, f) & 0xFFFF0000u);
}
__device__ __forceinline__ float tanh_fast(float x) {
    float e = __builtin_amdgcn_exp2f(x * 2.8853900817779268f); // 2*log2(e)
    float r = __builtin_amdgcn_rcpf(e + 1.0f);
    return __builtin_fmaf(-2.0f, r, 1.0f);
}
// split f[0..7] (k-consecutive) into hi/lo bf16x8 fragments
__device__ __forceinline__ void split8(const float* f, uint4& h, uint4& l) {
    h.x = pack_hi(f[0], f[1]); h.y = pack_hi(f[2], f[3]);
    h.z = pack_hi(f[4], f[5]); h.w = pack_hi(f[6], f[7]);
    l.x = pack_hi(f[0] - hi_part(f[0]), f[1] - hi_part(f[1]));
    l.y = pack_hi(f[2] - hi_part(f[2]), f[3] - hi_part(f[3]));
    l.z = pack_hi(f[4] - hi_part(f[4]), f[5] - hi_part(f[5]));
    l.w = pack_hi(f[6] - hi_part(f[6]), f[7] - hi_part(f[7]));
}

// Workspace layout (ushort elements):
//  whi [0, 2097152)  wlo [2097152, 4194304)   - 8192n x 256k, tiled
//  xhi [4194304, 5242880) xlo [5242880, 6291456) - 4096b x 256k, tiled
// tile layout: plane[((row>>4)*32 + koct)*128 + (row&15)*8 + j], k = koct*8+j
#define W_ELEMS  2097152
#define X_ELEMS  1048576
#define WS_NEED  (12u * 1024u * 1024u)

// ---- fused prep: blocks [0,1024) do W, [1024,1536) do x ----
// (r15 proved folding x-conversion into the MAIN kernel regresses — the
// f32+split8 chain sinks the A-prefetch. A separate prep kernel is fine;
// fusing the two PREP kernels just saves one graph-node launch.)
__global__ __launch_bounds__(256) void prep_kernel(
    const float* __restrict__ W, const float* __restrict__ x,
    ushort* __restrict__ whi, ushort* __restrict__ wlo,
    ushort* __restrict__ xhi, ushort* __restrict__ xlo)
{
    const int wg = blockIdx.x;
    if (wg < 1024) {                                   // W part: 32x32 tiles
        const int n    = (wg & 31) * 256 + threadIdx.x;   // 0..8191
        const int koct = wg >> 5;                         // 0..31
        float f[8];
        #pragma unroll
        for (int j = 0; j < 8; ++j)
            f[j] = __builtin_nontemporal_load(&W[(size_t)(koct * 8 + j) * NCOL + n]);
        uint4 h, l;
        split8(f, h, l);
        const size_t o = ((size_t)((n >> 4) * 32 + koct) * 16 + (n & 15)) * 8;
        *(uint4*)(whi + o) = h;
        *(uint4*)(wlo + o) = l;
    } else {                                           // x part: 16x32 tiles
        const int id   = wg - 1024;                       // 0..511
        const int b    = (id & 15) * 256 + threadIdx.x;   // 0..4095
        const int koct = id >> 4;                         // 0..31
        float f[8];
        fvec4 v0 = __builtin_nontemporal_load((const fvec4*)&x[(size_t)b * IN_DIM + koct * 8]);
        fvec4 v1 = __builtin_nontemporal_load((const fvec4*)&x[(size_t)b * IN_DIM + koct * 8 + 4]);
        f[0] = v0.x; f[1] = v0.y; f[2] = v0.z; f[3] = v0.w;
        f[4] = v1.x; f[5] = v1.y; f[6] = v1.z; f[7] = v1.w;
        uint4 h, l;
        split8(f, h, l);
        const size_t o = ((size_t)((b >> 4) * 32 + koct) * 16 + (b & 15)) * 8;
        *(uint4*)(xhi + o) = h;
        *(uint4*)(xlo + o) = l;
    }
}

// ---- main: 8-deep pipeline, 4-koct sub-chunks, 16 KB LDS total ----
// Experiment r18: halve LDS 32->16 KB to test whether LDS caps blocks/CU
// (occupancy stuck at 3 blocks under both (256,3) and (256,4) with regs and
// LDS both nominally allowing 5). Same DMA bytes, same MFMA count; 8 barriers.
// r4: (256,8) spills. r12: dual-tile accs spill. r15: in-kernel x conversion
// sinks the prefetch. out_mean store CACHED (r8: nt 4B = 8-16x write amp).
// hq loads CACHED. out_new store nt (r11/r13 A/B: nt wins the bench).
__global__ __launch_bounds__(256, 4) void mqc_main_kernel(
    const ushort* __restrict__ xhi, const ushort* __restrict__ xlo,
    const ushort* __restrict__ whi, const ushort* __restrict__ wlo,
    const float* __restrict__ hq,
    float* __restrict__ out_mean, float* __restrict__ out_new)
{
    // 2 buffers x (4 ntiles x 4 kl x 16 l16 x 8) per plane = 2 x 4 KB per plane
    __shared__ ushort sBh[4096], sBl[4096];    // 8 KiB + 8 KiB

    const int t     = threadIdx.x;
    const int lane  = t & 63;
    const int w     = t >> 6;           // wave 0..3 -> rows w*32..w*32+31
    const int lquad = lane >> 4;        // 0..3
    const int l16   = lane & 15;

    // XCD-clustered bijective block mapping (4096 = 8 xcd * 4 rowg * 128 colg)
    const int wgid = blockIdx.x;
    const int xcd  = wgid & 7;
    const int q    = wgid >> 3;
    const int rowg = (xcd << 2) | (q & 3);   // 0..31
    const int colg = q >> 2;                 // 0..127
    const int row0 = rowg * BM;
    const int col0 = colg * BN;
    const int btile0 = (row0 >> 4) + w * 2;
    const int ntile0 = col0 >> 4;

    f32x4 acc[2][4] = {};               // [mi][ni]; D[n][b]: row=n, col=b

    // Stage one 4-koct sub-chunk of B (8 KB) into buffer BUF via DMA w16.
    // itc 0..1, c = itc*4 + w in 0..7: plane = c>>2, nt = c&3.
    // One instr = 64 lanes x 16B = 1KB = one nt: lane covers kl=lane>>4,
    // l16=lane&15; dst = BUF*2048 + nt*512 + lane*8 (lane-linear).
    #define STAGE(BUF, KOCT0) {                                                     \
        _Pragma("unroll")                                                           \
        for (int itc = 0; itc < 2; ++itc) {                                         \
            const int c  = itc * 4 + w;                                             \
            const int nt = c & 3;                                                   \
            const ushort* srcp = ((c >> 2) ? wlo : whi)                             \
                + ((size_t)(ntile0 + nt) * 32 + (KOCT0) + (lane >> 4)) * 128        \
                + (lane & 15) * 8;                                                  \
            ushort* dstp = ((c >> 2) ? sBl : sBh) + (BUF) * 2048 + nt * 512;        \
            __builtin_amdgcn_global_load_lds((as1_uint*)srcp, (as3_uint*)dstp,      \
                                             16, 0, 0);                             \
        }                                                                           \
    }

    // prefetch A fragments for the 1 k-step of sub-chunk at KOCT0 into regs
    #define APREF(AH, AL, KOCT0) {                                                  \
        const int koct = (KOCT0) + lquad;                                           \
        _Pragma("unroll")                                                           \
        for (int mi = 0; mi < 2; ++mi) {                                            \
            const size_t o = ((size_t)(btile0 + mi) * 32 + koct) * 128 + l16 * 8;   \
            AH[mi] = *(const bf16x8*)(xhi + o);                                     \
            AL[mi] = *(const bf16x8*)(xlo + o);                                     \
        }                                                                           \
    }

    // 1 MFMA k-step over buffer BUF using prefetched A regs (48 MFMAs)
    #define KSTEP(BUF, AH, AL) {                                                    \
        const int bidx = (BUF) * 2048 + lquad * 128 + l16 * 8;                      \
        bf16x8 bH[4], bL[4];                                                        \
        _Pragma("unroll")                                                           \
        for (int ni = 0; ni < 4; ++ni) {                                            \
            bH[ni] = *(const bf16x8*)(sBh + ni * 512 + bidx);                       \
            bL[ni] = *(const bf16x8*)(sBl + ni * 512 + bidx);                       \
        }                                                                           \
        _Pragma("unroll")                                                           \
        for (int mi = 0; mi < 2; ++mi)                                              \
            _Pragma("unroll")                                                       \
            for (int ni = 0; ni < 4; ++ni)                                          \
                acc[mi][ni] = __builtin_amdgcn_mfma_f32_16x16x32_bf16(bH[ni], AH[mi], acc[mi][ni], 0, 0, 0); \
        _Pragma("unroll")                                                           \
        for (int mi = 0; mi < 2; ++mi)                                              \
            _Pragma("unroll")                                                       \
            for (int ni = 0; ni < 4; ++ni)                                          \
                acc[mi][ni] = __builtin_amdgcn_mfma_f32_16x16x32_bf16(bH[ni], AL[mi], acc[mi][ni], 0, 0, 0); \
        _Pragma("unroll")                                                           \
        for (int mi = 0; mi < 2; ++mi)                                              \
            _Pragma("unroll")                                                       \
            for (int ni = 0; ni < 4; ++ni)                                          \
                acc[mi][ni] = __builtin_amdgcn_mfma_f32_16x16x32_bf16(bL[ni], AH[mi], acc[mi][ni], 0, 0, 0); \
    }

    bf16x8 AaH[2], AaL[2], AbH[2], AbL[2];
    fvec4 hv[2][4];

    // 8 sub-chunks of 4 koct: 0,4,...,28. Double-buffered pipeline.
    STAGE(0, 0);   APREF(AaH, AaL, 0);
    __syncthreads();                        // sub-chunk 0 ready (exposed wait)
    STAGE(1, 4);   APREF(AbH, AbL, 4);
    KSTEP(0, AaH, AaL);
    __syncthreads();
    STAGE(0, 8);   APREF(AaH, AaL, 8);
    KSTEP(1, AbH, AbL);
    __syncthreads();
    STAGE(1, 12);  APREF(AbH, AbL, 12);
    KSTEP(0, AaH, AaL);
    __syncthreads();
    STAGE(0, 16);  APREF(AaH, AaL, 16);
    KSTEP(1, AbH, AbL);
    __syncthreads();
    STAGE(1, 20);  APREF(AbH, AbL, 20);
    KSTEP(0, AaH, AaL);
    __syncthreads();
    STAGE(0, 24);  APREF(AaH, AaL, 24);
    KSTEP(1, AbH, AbL);
    __syncthreads();
    STAGE(1, 28);  APREF(AbH, AbL, 28);
    // epilogue hq prefetch (cached): covered by the last two k-steps
    #pragma unroll
    for (int mi = 0; mi < 2; ++mi) {
        const int b = row0 + w * 32 + mi * 16 + l16;
        #pragma unroll
        for (int ni = 0; ni < 4; ++ni) {
            const int n = col0 + ni * 16 + lquad * 4;
            hv[mi][ni] = *(const fvec4*)&hq[(size_t)b * NCOL + n];
        }
    }
    KSTEP(0, AaH, AaL);
    __syncthreads();                        // sub-chunk 7 ready (covered)
    KSTEP(1, AbH, AbL);
    #undef STAGE
    #undef APREF
    #undef KSTEP

    // ---- fused epilogue: tanh(C + 0.9*h), nt out_new store, cached out_mean.
    //      D[n][b]: n = col0+ni*16+4*lquad+reg, b = row0+w*32+mi*16+l16
    #pragma unroll
    for (int mi = 0; mi < 2; ++mi) {
        const int b = row0 + w * 32 + mi * 16 + l16;
        #pragma unroll
        for (int ni = 0; ni < 4; ++ni) {
            const int n = col0 + ni * 16 + lquad * 4;
            fvec4 ov;
            ov.x = tanh_fast(__builtin_fmaf(0.9f, hv[mi][ni].x, acc[mi][ni][0]));
            ov.y = tanh_fast(__builtin_fmaf(0.9f, hv[mi][ni].y, acc[mi][ni][1]));
            ov.z = tanh_fast(__builtin_fmaf(0.9f, hv[mi][ni].z, acc[mi][ni][2]));
            ov.w = tanh_fast(__builtin_fmaf(0.9f, hv[mi][ni].w, acc[mi][ni][3]));
            __builtin_nontemporal_store(ov, (fvec4*)&out_new[(size_t)b * NCOL + n]);
            float s = (ov.x + ov.y) + (ov.z + ov.w);
            s += __shfl_xor(s, 16);
            s += __shfl_xor(s, 32);
            if (lquad == 0)
                out_mean[(size_t)b * HID + (col0 >> 4) + ni] = s * 0.0625f;
        }
    }
}

// ================= fallback (round-5 proven kernel, used if ws too small) ======
#define BKF 64
__device__ __forceinline__ int swz(int row, int byteoff) {
    return byteoff ^ ((((row & 7) ^ ((row >> 3) & 7))) << 4);
}
__global__ __launch_bounds__(256, 4) void mqc_fallback_kernel(
    const float* __restrict__ x, const float* __restrict__ hq,
    const float* __restrict__ W,
    float* __restrict__ out_mean, float* __restrict__ out_new)
{
    __shared__ char sB[2 * BN * BKF * 2];
    char* const sB_hi = sB;
    char* const sB_lo = sB + BN * BKF * 2;
    const int t = threadIdx.x, lane = t & 63, w = t >> 6;
    const int lquad = lane >> 4, l16 = lane & 15;
    const int row0 = blockIdx.x * BM, col0 = blockIdx.y * BN;
    const int k0 = (t >> 4) * 4, n0 = (t & 15) * 4;
    f32x4 acc[2][4] = {};
    for (int kt = 0; kt < IN_DIM / BKF; ++kt) {
        float4 ax[2][2][2];
        #pragma unroll
        for (int mi = 0; mi < 2; ++mi)
            #pragma unroll
            for (int ks = 0; ks < 2; ++ks) {
                const float* p = &x[(size_t)(row0 + w * 32 + mi * 16 + l16) * IN_DIM
                                    + kt * BKF + ks * 32 + lquad * 8];
                ax[mi][ks][0] = *(const float4*)(p);
                ax[mi][ks][1] = *(const float4*)(p + 4);
            }
        float4 wrow[4];
        #pragma unroll
        for (int r = 0; r < 4; ++r)
            wrow[r] = *(const float4*)(&W[(size_t)(kt * BKF + k0 + r) * NCOL + col0 + n0]);
        #pragma unroll
        for (int c = 0; c < 4; ++c) {
            const float f0 = ((const float*)&wrow[0])[c];
            const float f1 = ((const float*)&wrow[1])[c];
            const float f2 = ((const float*)&wrow[2])[c];
            const float f3 = ((const float*)&wrow[3])[c];
            uint2 hv2, lv2;
            hv2.x = pack_hi(f0, f1); hv2.y = pack_hi(f2, f3);
            lv2.x = pack_hi(f0 - hi_part(f0), f1 - hi_part(f1));
            lv2.y = pack_hi(f2 - hi_part(f2), f3 - hi_part(f3));
            const int off = swz(n0 + c, (n0 + c) * (BKF * 2) + k0 * 2);
            *(uint2*)(sB_hi + off) = hv2;
            *(uint2*)(sB_lo + off) = lv2;
        }
        __syncthreads();
        #pragma unroll
        for (int ks = 0; ks < 2; ++ks) {
            bf16x8 aH[2], aL[2];
            #pragma unroll
            for (int mi = 0; mi < 2; ++mi) {
                uint4 h, l;
                split8((const float*)&ax[mi][ks][0], h, l);
                aH[mi] = __builtin_bit_cast(bf16x8, h);
                aL[mi] = __builtin_bit_cast(bf16x8, l);
            }
            const int kb = ks * 64 + lquad * 16;
            bf16x8 bH[4], bL[4];
            #pragma unroll
            for (int ni = 0; ni < 4; ++ni) {
                const int row = ni * 16 + l16;
                bH[ni] = *(const bf16x8*)(sB_hi + swz(row, row * (BKF * 2) + kb));
            }
            #pragma unroll
            for (int mi = 0; mi < 2; ++mi)
                #pragma unroll
                for (int ni = 0; ni < 4; ++ni)
                    acc[mi][ni] = __builtin_amdgcn_mfma_f32_16x16x32_bf16(bH[ni], aH[mi], acc[mi][ni], 0, 0, 0);
            #pragma unroll
            for (int mi = 0; mi < 2; ++mi)
                #pragma unroll
                for (int ni = 0; ni < 4; ++ni)
                    acc[mi][ni] = __builtin_amdgcn_mfma_f32_16x16x32_bf16(bH[ni], aL[mi], acc[mi][ni], 0, 0, 0);
            #pragma unroll
            for (int ni = 0; ni < 4; ++ni) {
                const int row = ni * 16 + l16;
                bL[ni] = *(const bf16x8*)(sB_lo + swz(row, row * (BKF * 2) + kb));
            }
            #pragma unroll
            for (int mi = 0; mi < 2; ++mi)
                #pragma unroll
                for (int ni = 0; ni < 4; ++ni)
                    acc[mi][ni] = __builtin_amdgcn_mfma_f32_16x16x32_bf16(bL[ni], aH[mi], acc[mi][ni], 0, 0, 0);
        }
        __syncthreads();
    }
    #pragma unroll
    for (int mi = 0; mi < 2; ++mi) {
        const int b = row0 + w * 32 + mi * 16 + l16;
        #pragma unroll
        for (int ni = 0; ni < 4; ++ni) {
            const int n = col0 + ni * 16 + lquad * 4;
            const float4 hv = *(const float4*)(&hq[(size_t)b * NCOL + n]);
            float4 ov;
            ov.x = tanh_fast(__builtin_fmaf(0.9f, hv.x, acc[mi][ni][0]));
            ov.y = tanh_fast(__builtin_fmaf(0.9f, hv.y, acc[mi][ni][1]));
            ov.z = tanh_fast(__builtin_fmaf(0.9f, hv.z, acc[mi][ni][2]));
            ov.w = tanh_fast(__builtin_fmaf(0.9f, hv.w, acc[mi][ni][3]));
            *(float4*)(&out_new[(size_t)b * NCOL + n]) = ov;
            float s = (ov.x + ov.y) + (ov.z + ov.w);
            s += __shfl_xor(s, 16);
            s += __shfl_xor(s, 32);
            if (lquad == 0)
                out_mean[(size_t)b * HID + (col0 >> 4) + ni] = s * 0.0625f;
        }
    }
}

extern "C" void kernel_launch(void* const* d_in, const int* in_sizes, int n_in,
                              void* d_out, int out_size, void* d_ws, size_t ws_size,
                              hipStream_t stream) {
    const float* x  = (const float*)d_in[0];   // [4096, 256]
    const float* hq = (const float*)d_in[1];   // [4096, 512, 16]
    const float* W  = (const float*)d_in[2];   // [256, 512, 16]

    float* out_mean = (float*)d_out;                          // [4096, 512]
    float* out_new  = (float*)d_out + (size_t)BATCH * HID;    // [4096, 512, 16]

    if (ws_size >= WS_NEED) {
        ushort* whi = (ushort*)d_ws;
        ushort* wlo = whi + W_ELEMS;
        ushort* xhi = wlo + W_ELEMS;
        ushort* xlo = xhi + X_ELEMS;
        prep_kernel<<<dim3(1536), 256, 0, stream>>>(W, x, whi, wlo, xhi, xlo);
        mqc_main_kernel<<<dim3(BATCH * NCOL / (BM * BN)), 256, 0, stream>>>(
            xhi, xlo, whi, wlo, hq, out_mean, out_new);
    } else {
        mqc_fallback_kernel<<<dim3(BATCH / BM, NCOL / BN), 256, 0, stream>>>(
            x, hq, W, out_mean, out_new);
    }
}

// Round 19
// 89.559 us; speedup vs baseline: 1.1743x; 1.0050x over previous
//
#include <hip/hip_runtime.h>

// Problem dims (fixed by reference)
#define BATCH  4096
#define IN_DIM 256
#define HID    512
#define NCOL   8192            // HID * STATES

// Main tiling: 256x64 block tile, 8 waves stacked on M (32 rows each)
#define BM 256
#define BN 64

typedef __attribute__((ext_vector_type(8))) short bf16x8;
typedef __attribute__((ext_vector_type(4))) float f32x4;
typedef __attribute__((ext_vector_type(4))) float fvec4;   // clang-native, nt-compatible

typedef __attribute__((address_space(1))) const unsigned as1_uint;
typedef __attribute__((address_space(3))) unsigned       as3_uint;

// pack bf16(f0) into low16, bf16(f1) into high16 (truncation) — 1 v_perm_b32
__device__ __forceinline__ uint pack_hi(float f0, float f1) {
    return __builtin_amdgcn_perm(__builtin_bit_cast(uint, f1),
                                 __builtin_bit_cast(uint, f0), 0x07060302u);
}
__device__ __forceinline__ float hi_part(float f) {
    return __builtin_bit_cast(float, __builtin_bit_cast(uint, f) & 0xFFFF0000u);
}
__device__ __forceinline__ float tanh_fast(float x) {
    float e = __builtin_amdgcn_exp2f(x * 2.8853900817779268f); // 2*log2(e)
    float r = __builtin_amdgcn_rcpf(e + 1.0f);
    return __builtin_fmaf(-2.0f, r, 1.0f);
}
// split f[0..7] (k-consecutive) into hi/lo bf16x8 fragments
__device__ __forceinline__ void split8(const float* f, uint4& h, uint4& l) {
    h.x = pack_hi(f[0], f[1]); h.y = pack_hi(f[2], f[3]);
    h.z = pack_hi(f[4], f[5]); h.w = pack_hi(f[6], f[7]);
    l.x = pack_hi(f[0] - hi_part(f[0]), f[1] - hi_part(f[1]));
    l.y = pack_hi(f[2] - hi_part(f[2]), f[3] - hi_part(f[3]));
    l.z = pack_hi(f[4] - hi_part(f[4]), f[5] - hi_part(f[5]));
    l.w = pack_hi(f[6] - hi_part(f[6]), f[7] - hi_part(f[7]));
}

// Workspace layout (ushort elements):
//  whi [0, 2097152)  wlo [2097152, 4194304)   - 8192n x 256k, tiled
//  xhi [4194304, 5242880) xlo [5242880, 6291456) - 4096b x 256k, tiled
// tile layout: plane[((row>>4)*32 + koct)*128 + (row&15)*8 + j], k = koct*8+j
#define W_ELEMS  2097152
#define X_ELEMS  1048576
#define WS_NEED  (12u * 1024u * 1024u)

// ---- fused prep: blocks [0,1024) do W, [1024,1536) do x ----
__global__ __launch_bounds__(256) void prep_kernel(
    const float* __restrict__ W, const float* __restrict__ x,
    ushort* __restrict__ whi, ushort* __restrict__ wlo,
    ushort* __restrict__ xhi, ushort* __restrict__ xlo)
{
    const int wg = blockIdx.x;
    if (wg < 1024) {                                   // W part: 32x32 tiles
        const int n    = (wg & 31) * 256 + threadIdx.x;   // 0..8191
        const int koct = wg >> 5;                         // 0..31
        float f[8];
        #pragma unroll
        for (int j = 0; j < 8; ++j)
            f[j] = __builtin_nontemporal_load(&W[(size_t)(koct * 8 + j) * NCOL + n]);
        uint4 h, l;
        split8(f, h, l);
        const size_t o = ((size_t)((n >> 4) * 32 + koct) * 16 + (n & 15)) * 8;
        *(uint4*)(whi + o) = h;
        *(uint4*)(wlo + o) = l;
    } else {                                           // x part: 16x32 tiles
        const int id   = wg - 1024;                       // 0..511
        const int b    = (id & 15) * 256 + threadIdx.x;   // 0..4095
        const int koct = id >> 4;                         // 0..31
        float f[8];
        fvec4 v0 = __builtin_nontemporal_load((const fvec4*)&x[(size_t)b * IN_DIM + koct * 8]);
        fvec4 v1 = __builtin_nontemporal_load((const fvec4*)&x[(size_t)b * IN_DIM + koct * 8 + 4]);
        f[0] = v0.x; f[1] = v0.y; f[2] = v0.z; f[3] = v0.w;
        f[4] = v1.x; f[5] = v1.y; f[6] = v1.z; f[7] = v1.w;
        uint4 h, l;
        split8(f, h, l);
        const size_t o = ((size_t)((b >> 4) * 32 + koct) * 16 + (b & 15)) * 8;
        *(uint4*)(xhi + o) = h;
        *(uint4*)(xlo + o) = l;
    }
}

// ---- main: 512-thread blocks (8 waves, BM=256), 8-deep pipeline, 16 KB LDS ----
// Experiment r19: residency appears BLOCK-granular (3 blocks = 12 waves/CU
// under every bound/LDS tried). Bigger blocks pack more waves per residency
// slot: 2 blocks x 8 waves = 16 waves/CU. Same per-wave work; B-tile now
// amortized over 8 waves; STAGE = exactly 1 DMA instr per wave.
// r4: (256,8) reg-cap 64 spills. r12: dual-tile accs spill. r15: in-kernel x
// conversion sinks the prefetch. out_mean store CACHED (r8: nt 4B = 8-16x
// write amp). hq loads CACHED. out_new store nt (r11/r13 A/B: nt wins).
__global__ __launch_bounds__(512, 4) void mqc_main_kernel(
    const ushort* __restrict__ xhi, const ushort* __restrict__ xlo,
    const ushort* __restrict__ whi, const ushort* __restrict__ wlo,
    const float* __restrict__ hq,
    float* __restrict__ out_mean, float* __restrict__ out_new)
{
    // 2 buffers x (4 ntiles x 4 kl x 16 l16 x 8) per plane = 2 x 4 KB per plane
    __shared__ ushort sBh[4096], sBl[4096];    // 8 KiB + 8 KiB

    const int t     = threadIdx.x;
    const int lane  = t & 63;
    const int w     = t >> 6;           // wave 0..7 -> rows w*32..w*32+31
    const int lquad = lane >> 4;        // 0..3
    const int l16   = lane & 15;

    // XCD-clustered bijective block mapping (2048 = 8 xcd * 2 rowg * 128 colg)
    const int wgid = blockIdx.x;
    const int xcd  = wgid & 7;
    const int q    = wgid >> 3;              // 0..255
    const int rowg = (xcd << 1) | (q & 1);   // 0..15
    const int colg = q >> 1;                 // 0..127
    const int row0 = rowg * BM;
    const int col0 = colg * BN;
    const int btile0 = (row0 >> 4) + w * 2;
    const int ntile0 = col0 >> 4;

    f32x4 acc[2][4] = {};               // [mi][ni]; D[n][b]: row=n, col=b

    // Stage one 4-koct sub-chunk of B (8 KB) into buffer BUF: 8 DMA instrs,
    // exactly one per wave. c = w: plane = c>>2, nt = c&3. Each instr:
    // 64 lanes x 16B = 1 KB = one ntile (kl=lane>>4, l16=lane&15).
    #define STAGE(BUF, KOCT0) {                                                     \
        const int nt = w & 3;                                                       \
        const ushort* srcp = ((w >> 2) ? wlo : whi)                                 \
            + ((size_t)(ntile0 + nt) * 32 + (KOCT0) + (lane >> 4)) * 128            \
            + (lane & 15) * 8;                                                      \
        ushort* dstp = ((w >> 2) ? sBl : sBh) + (BUF) * 2048 + nt * 512;            \
        __builtin_amdgcn_global_load_lds((as1_uint*)srcp, (as3_uint*)dstp,          \
                                         16, 0, 0);                                 \
    }

    // prefetch A fragments for the 1 k-step of sub-chunk at KOCT0 into regs
    #define APREF(AH, AL, KOCT0) {                                                  \
        const int koct = (KOCT0) + lquad;                                           \
        _Pragma("unroll")                                                           \
        for (int mi = 0; mi < 2; ++mi) {                                            \
            const size_t o = ((size_t)(btile0 + mi) * 32 + koct) * 128 + l16 * 8;   \
            AH[mi] = *(const bf16x8*)(xhi + o);                                     \
            AL[mi] = *(const bf16x8*)(xlo + o);                                     \
        }                                                                           \
    }

    // 1 MFMA k-step over buffer BUF using prefetched A regs (24 MFMAs/wave)
    #define KSTEP(BUF, AH, AL) {                                                    \
        const int bidx = (BUF) * 2048 + lquad * 128 + l16 * 8;                      \
        bf16x8 bH[4], bL[4];                                                        \
        _Pragma("unroll")                                                           \
        for (int ni = 0; ni < 4; ++ni) {                                            \
            bH[ni] = *(const bf16x8*)(sBh + ni * 512 + bidx);                       \
            bL[ni] = *(const bf16x8*)(sBl + ni * 512 + bidx);                       \
        }                                                                           \
        _Pragma("unroll")                                                           \
        for (int mi = 0; mi < 2; ++mi)                                              \
            _Pragma("unroll")                                                       \
            for (int ni = 0; ni < 4; ++ni)                                          \
                acc[mi][ni] = __builtin_amdgcn_mfma_f32_16x16x32_bf16(bH[ni], AH[mi], acc[mi][ni], 0, 0, 0); \
        _Pragma("unroll")                                                           \
        for (int mi = 0; mi < 2; ++mi)                                              \
            _Pragma("unroll")                                                       \
            for (int ni = 0; ni < 4; ++ni)                                          \
                acc[mi][ni] = __builtin_amdgcn_mfma_f32_16x16x32_bf16(bH[ni], AL[mi], acc[mi][ni], 0, 0, 0); \
        _Pragma("unroll")                                                           \
        for (int mi = 0; mi < 2; ++mi)                                              \
            _Pragma("unroll")                                                       \
            for (int ni = 0; ni < 4; ++ni)                                          \
                acc[mi][ni] = __builtin_amdgcn_mfma_f32_16x16x32_bf16(bL[ni], AH[mi], acc[mi][ni], 0, 0, 0); \
    }

    bf16x8 AaH[2], AaL[2], AbH[2], AbL[2];
    fvec4 hv[2][4];

    // 8 sub-chunks of 4 koct: 0,4,...,28. Double-buffered pipeline.
    STAGE(0, 0);   APREF(AaH, AaL, 0);
    __syncthreads();                        // sub-chunk 0 ready (exposed wait)
    STAGE(1, 4);   APREF(AbH, AbL, 4);
    KSTEP(0, AaH, AaL);
    __syncthreads();
    STAGE(0, 8);   APREF(AaH, AaL, 8);
    KSTEP(1, AbH, AbL);
    __syncthreads();
    STAGE(1, 12);  APREF(AbH, AbL, 12);
    KSTEP(0, AaH, AaL);
    __syncthreads();
    STAGE(0, 16);  APREF(AaH, AaL, 16);
    KSTEP(1, AbH, AbL);
    __syncthreads();
    STAGE(1, 20);  APREF(AbH, AbL, 20);
    KSTEP(0, AaH, AaL);
    __syncthreads();
    STAGE(0, 24);  APREF(AaH, AaL, 24);
    KSTEP(1, AbH, AbL);
    __syncthreads();
    STAGE(1, 28);  APREF(AbH, AbL, 28);
    // epilogue hq prefetch (cached): covered by the last two k-steps
    #pragma unroll
    for (int mi = 0; mi < 2; ++mi) {
        const int b = row0 + w * 32 + mi * 16 + l16;
        #pragma unroll
        for (int ni = 0; ni < 4; ++ni) {
            const int n = col0 + ni * 16 + lquad * 4;
            hv[mi][ni] = *(const fvec4*)&hq[(size_t)b * NCOL + n];
        }
    }
    KSTEP(0, AaH, AaL);
    __syncthreads();                        // sub-chunk 7 ready (covered)
    KSTEP(1, AbH, AbL);
    #undef STAGE
    #undef APREF
    #undef KSTEP

    // ---- fused epilogue: tanh(C + 0.9*h), nt out_new store, cached out_mean.
    //      D[n][b]: n = col0+ni*16+4*lquad+reg, b = row0+w*32+mi*16+l16
    #pragma unroll
    for (int mi = 0; mi < 2; ++mi) {
        const int b = row0 + w * 32 + mi * 16 + l16;
        #pragma unroll
        for (int ni = 0; ni < 4; ++ni) {
            const int n = col0 + ni * 16 + lquad * 4;
            fvec4 ov;
            ov.x = tanh_fast(__builtin_fmaf(0.9f, hv[mi][ni].x, acc[mi][ni][0]));
            ov.y = tanh_fast(__builtin_fmaf(0.9f, hv[mi][ni].y, acc[mi][ni][1]));
            ov.z = tanh_fast(__builtin_fmaf(0.9f, hv[mi][ni].z, acc[mi][ni][2]));
            ov.w = tanh_fast(__builtin_fmaf(0.9f, hv[mi][ni].w, acc[mi][ni][3]));
            __builtin_nontemporal_store(ov, (fvec4*)&out_new[(size_t)b * NCOL + n]);
            float s = (ov.x + ov.y) + (ov.z + ov.w);
            s += __shfl_xor(s, 16);
            s += __shfl_xor(s, 32);
            if (lquad == 0)
                out_mean[(size_t)b * HID + (col0 >> 4) + ni] = s * 0.0625f;
        }
    }
}

// ================= fallback (round-5 proven kernel, used if ws too small) ======
#define BMF 128
#define BKF 64
__device__ __forceinline__ int swz(int row, int byteoff) {
    return byteoff ^ ((((row & 7) ^ ((row >> 3) & 7))) << 4);
}
__global__ __launch_bounds__(256, 4) void mqc_fallback_kernel(
    const float* __restrict__ x, const float* __restrict__ hq,
    const float* __restrict__ W,
    float* __restrict__ out_mean, float* __restrict__ out_new)
{
    __shared__ char sB[2 * BN * BKF * 2];
    char* const sB_hi = sB;
    char* const sB_lo = sB + BN * BKF * 2;
    const int t = threadIdx.x, lane = t & 63, w = t >> 6;
    const int lquad = lane >> 4, l16 = lane & 15;
    const int row0 = blockIdx.x * BMF, col0 = blockIdx.y * BN;
    const int k0 = (t >> 4) * 4, n0 = (t & 15) * 4;
    f32x4 acc[2][4] = {};
    for (int kt = 0; kt < IN_DIM / BKF; ++kt) {
        float4 ax[2][2][2];
        #pragma unroll
        for (int mi = 0; mi < 2; ++mi)
            #pragma unroll
            for (int ks = 0; ks < 2; ++ks) {
                const float* p = &x[(size_t)(row0 + w * 32 + mi * 16 + l16) * IN_DIM
                                    + kt * BKF + ks * 32 + lquad * 8];
                ax[mi][ks][0] = *(const float4*)(p);
                ax[mi][ks][1] = *(const float4*)(p + 4);
            }
        float4 wrow[4];
        #pragma unroll
        for (int r = 0; r < 4; ++r)
            wrow[r] = *(const float4*)(&W[(size_t)(kt * BKF + k0 + r) * NCOL + col0 + n0]);
        #pragma unroll
        for (int c = 0; c < 4; ++c) {
            const float f0 = ((const float*)&wrow[0])[c];
            const float f1 = ((const float*)&wrow[1])[c];
            const float f2 = ((const float*)&wrow[2])[c];
            const float f3 = ((const float*)&wrow[3])[c];
            uint2 hv2, lv2;
            hv2.x = pack_hi(f0, f1); hv2.y = pack_hi(f2, f3);
            lv2.x = pack_hi(f0 - hi_part(f0), f1 - hi_part(f1));
            lv2.y = pack_hi(f2 - hi_part(f2), f3 - hi_part(f3));
            const int off = swz(n0 + c, (n0 + c) * (BKF * 2) + k0 * 2);
            *(uint2*)(sB_hi + off) = hv2;
            *(uint2*)(sB_lo + off) = lv2;
        }
        __syncthreads();
        #pragma unroll
        for (int ks = 0; ks < 2; ++ks) {
            bf16x8 aH[2], aL[2];
            #pragma unroll
            for (int mi = 0; mi < 2; ++mi) {
                uint4 h, l;
                split8((const float*)&ax[mi][ks][0], h, l);
                aH[mi] = __builtin_bit_cast(bf16x8, h);
                aL[mi] = __builtin_bit_cast(bf16x8, l);
            }
            const int kb = ks * 64 + lquad * 16;
            bf16x8 bH[4], bL[4];
            #pragma unroll
            for (int ni = 0; ni < 4; ++ni) {
                const int row = ni * 16 + l16;
                bH[ni] = *(const bf16x8*)(sB_hi + swz(row, row * (BKF * 2) + kb));
            }
            #pragma unroll
            for (int mi = 0; mi < 2; ++mi)
                #pragma unroll
                for (int ni = 0; ni < 4; ++ni)
                    acc[mi][ni] = __builtin_amdgcn_mfma_f32_16x16x32_bf16(bH[ni], aH[mi], acc[mi][ni], 0, 0, 0);
            #pragma unroll
            for (int mi = 0; mi < 2; ++mi)
                #pragma unroll
                for (int ni = 0; ni < 4; ++ni)
                    acc[mi][ni] = __builtin_amdgcn_mfma_f32_16x16x32_bf16(bH[ni], aL[mi], acc[mi][ni], 0, 0, 0);
            #pragma unroll
            for (int ni = 0; ni < 4; ++ni) {
                const int row = ni * 16 + l16;
                bL[ni] = *(const bf16x8*)(sB_lo + swz(row, row * (BKF * 2) + kb));
            }
            #pragma unroll
            for (int mi = 0; mi < 2; ++mi)
                #pragma unroll
                for (int ni = 0; ni < 4; ++ni)
                    acc[mi][ni] = __builtin_amdgcn_mfma_f32_16x16x32_bf16(bL[ni], aH[mi], acc[mi][ni], 0, 0, 0);
        }
        __syncthreads();
    }
    #pragma unroll
    for (int mi = 0; mi < 2; ++mi) {
        const int b = row0 + w * 32 + mi * 16 + l16;
        #pragma unroll
        for (int ni = 0; ni < 4; ++ni) {
            const int n = col0 + ni * 16 + lquad * 4;
            const float4 hv = *(const float4*)(&hq[(size_t)b * NCOL + n]);
            float4 ov;
            ov.x = tanh_fast(__builtin_fmaf(0.9f, hv.x, acc[mi][ni][0]));
            ov.y = tanh_fast(__builtin_fmaf(0.9f, hv.y, acc[mi][ni][1]));
            ov.z = tanh_fast(__builtin_fmaf(0.9f, hv.z, acc[mi][ni][2]));
            ov.w = tanh_fast(__builtin_fmaf(0.9f, hv.w, acc[mi][ni][3]));
            *(float4*)(&out_new[(size_t)b * NCOL + n]) = ov;
            float s = (ov.x + ov.y) + (ov.z + ov.w);
            s += __shfl_xor(s, 16);
            s += __shfl_xor(s, 32);
            if (lquad == 0)
                out_mean[(size_t)b * HID + (col0 >> 4) + ni] = s * 0.0625f;
        }
    }
}

extern "C" void kernel_launch(void* const* d_in, const int* in_sizes, int n_in,
                              void* d_out, int out_size, void* d_ws, size_t ws_size,
                              hipStream_t stream) {
    const float* x  = (const float*)d_in[0];   // [4096, 256]
    const float* hq = (const float*)d_in[1];   // [4096, 512, 16]
    const float* W  = (const float*)d_in[2];   // [256, 512, 16]

    float* out_mean = (float*)d_out;                          // [4096, 512]
    float* out_new  = (float*)d_out + (size_t)BATCH * HID;    // [4096, 512, 16]

    if (ws_size >= WS_NEED) {
        ushort* whi = (ushort*)d_ws;
        ushort* wlo = whi + W_ELEMS;
        ushort* xhi = wlo + W_ELEMS;
        ushort* xlo = xhi + X_ELEMS;
        prep_kernel<<<dim3(1536), 256, 0, stream>>>(W, x, whi, wlo, xhi, xlo);
        mqc_main_kernel<<<dim3(BATCH * NCOL / (BM * BN)), 512, 0, stream>>>(
            xhi, xlo, whi, wlo, hq, out_mean, out_new);
    } else {
        mqc_fallback_kernel<<<dim3(BATCH / BMF, NCOL / BN), 256, 0, stream>>>(
            x, hq, W, out_mean, out_new);
    }
}

// Round 20
// 89.152 us; speedup vs baseline: 1.1796x; 1.0046x over previous
//
#include <hip/hip_runtime.h>

// Problem dims (fixed by reference)
#define BATCH  4096
#define IN_DIM 256
#define HID    512
#define NCOL   8192            // HID * STATES

// Main tiling: 256x64 block tile, 8 waves stacked on M (32 rows each)
#define BM 256
#define BN 64

typedef __attribute__((ext_vector_type(8))) short bf16x8;
typedef __attribute__((ext_vector_type(4))) float f32x4;
typedef __attribute__((ext_vector_type(4))) float fvec4;   // clang-native, nt-compatible

typedef __attribute__((address_space(1))) const unsigned as1_uint;
typedef __attribute__((address_space(3))) unsigned       as3_uint;

// pack bf16(f0) into low16, bf16(f1) into high16 (truncation) — 1 v_perm_b32
__device__ __forceinline__ uint pack_hi(float f0, float f1) {
    return __builtin_amdgcn_perm(__builtin_bit_cast(uint, f1),
                                 __builtin_bit_cast(uint, f0), 0x07060302u);
}
__device__ __forceinline__ float hi_part(float f) {
    return __builtin_bit_cast(float, __builtin_bit_cast(uint, f) & 0xFFFF0000u);
}
__device__ __forceinline__ float tanh_fast(float x) {
    float e = __builtin_amdgcn_exp2f(x * 2.8853900817779268f); // 2*log2(e)
    float r = __builtin_amdgcn_rcpf(e + 1.0f);
    return __builtin_fmaf(-2.0f, r, 1.0f);
}
// split f[0..7] (k-consecutive) into hi/lo bf16x8 fragments
__device__ __forceinline__ void split8(const float* f, uint4& h, uint4& l) {
    h.x = pack_hi(f[0], f[1]); h.y = pack_hi(f[2], f[3]);
    h.z = pack_hi(f[4], f[5]); h.w = pack_hi(f[6], f[7]);
    l.x = pack_hi(f[0] - hi_part(f[0]), f[1] - hi_part(f[1]));
    l.y = pack_hi(f[2] - hi_part(f[2]), f[3] - hi_part(f[3]));
    l.z = pack_hi(f[4] - hi_part(f[4]), f[5] - hi_part(f[5]));
    l.w = pack_hi(f[6] - hi_part(f[6]), f[7] - hi_part(f[7]));
}

// Workspace layout (ushort elements):
//  whi [0, 2097152)  wlo [2097152, 4194304)   - 8192n x 256k, tiled
//  xhi [4194304, 5242880) xlo [5242880, 6291456) - 4096b x 256k, tiled
// tile layout: plane[((row>>4)*32 + koct)*128 + (row&15)*8 + j], k = koct*8+j
#define W_ELEMS  2097152
#define X_ELEMS  1048576
#define WS_NEED  (12u * 1024u * 1024u)

// ---- fused prep: blocks [0,1024) do W, [1024,1536) do x ----
__global__ __launch_bounds__(256) void prep_kernel(
    const float* __restrict__ W, const float* __restrict__ x,
    ushort* __restrict__ whi, ushort* __restrict__ wlo,
    ushort* __restrict__ xhi, ushort* __restrict__ xlo)
{
    const int wg = blockIdx.x;
    if (wg < 1024) {                                   // W part: 32x32 tiles
        const int n    = (wg & 31) * 256 + threadIdx.x;   // 0..8191
        const int koct = wg >> 5;                         // 0..31
        float f[8];
        #pragma unroll
        for (int j = 0; j < 8; ++j)
            f[j] = __builtin_nontemporal_load(&W[(size_t)(koct * 8 + j) * NCOL + n]);
        uint4 h, l;
        split8(f, h, l);
        const size_t o = ((size_t)((n >> 4) * 32 + koct) * 16 + (n & 15)) * 8;
        *(uint4*)(whi + o) = h;
        *(uint4*)(wlo + o) = l;
    } else {                                           // x part: 16x32 tiles
        const int id   = wg - 1024;                       // 0..511
        const int b    = (id & 15) * 256 + threadIdx.x;   // 0..4095
        const int koct = id >> 4;                         // 0..31
        float f[8];
        fvec4 v0 = __builtin_nontemporal_load((const fvec4*)&x[(size_t)b * IN_DIM + koct * 8]);
        fvec4 v1 = __builtin_nontemporal_load((const fvec4*)&x[(size_t)b * IN_DIM + koct * 8 + 4]);
        f[0] = v0.x; f[1] = v0.y; f[2] = v0.z; f[3] = v0.w;
        f[4] = v1.x; f[5] = v1.y; f[6] = v1.z; f[7] = v1.w;
        uint4 h, l;
        split8(f, h, l);
        const size_t o = ((size_t)((b >> 4) * 32 + koct) * 16 + (b & 15)) * 8;
        *(uint4*)(xhi + o) = h;
        *(uint4*)(xlo + o) = l;
    }
}

// ---- main: r19 body + T4 counted-vmcnt barriers ----
// __syncthreads() emits s_waitcnt vmcnt(0) before s_barrier, force-draining
// the just-issued STAGE DMA at EVERY phase barrier — the pipeline never
// actually overlapped. Replace with: s_waitcnt vmcnt(4) (own DMA done, the
// 4 A-loads may stay in flight; vmcnt(8) in the hv phase) + raw s_barrier.
// Issue order DMA-before-A-loads is pinned with sched_barrier(0).
// LDS safety: prev KSTEP's ds_reads are lgkm-consumed before the barrier;
// the overwriting DMA is issued after it. Compiler still emits its own
// counted waits for A-reg/hv consumption.
// r4: reg-cap 64 spills. r12: dual-tile accs spill. r15: in-kernel x
// conversion sinks the prefetch. out_mean store CACHED (r8: nt 4B = 8-16x
// write amp). hq loads CACHED. out_new store nt (r11/r13 A/B: nt wins).
__global__ __launch_bounds__(512, 4) void mqc_main_kernel(
    const ushort* __restrict__ xhi, const ushort* __restrict__ xlo,
    const ushort* __restrict__ whi, const ushort* __restrict__ wlo,
    const float* __restrict__ hq,
    float* __restrict__ out_mean, float* __restrict__ out_new)
{
    // 2 buffers x (4 ntiles x 4 kl x 16 l16 x 8) per plane = 2 x 4 KB per plane
    __shared__ ushort sBh[4096], sBl[4096];    // 8 KiB + 8 KiB

    const int t     = threadIdx.x;
    const int lane  = t & 63;
    const int w     = t >> 6;           // wave 0..7 -> rows w*32..w*32+31
    const int lquad = lane >> 4;        // 0..3
    const int l16   = lane & 15;

    // XCD-clustered bijective block mapping (2048 = 8 xcd * 2 rowg * 128 colg)
    const int wgid = blockIdx.x;
    const int xcd  = wgid & 7;
    const int q    = wgid >> 3;              // 0..255
    const int rowg = (xcd << 1) | (q & 1);   // 0..15
    const int colg = q >> 1;                 // 0..127
    const int row0 = rowg * BM;
    const int col0 = colg * BN;
    const int btile0 = (row0 >> 4) + w * 2;
    const int ntile0 = col0 >> 4;

    f32x4 acc[2][4] = {};               // [mi][ni]; D[n][b]: row=n, col=b

    #define SB() __builtin_amdgcn_sched_barrier(0)
    // counted barrier: own DMA (oldest) complete, N newer vmem ops may fly
    #define BARC(N) { asm volatile("s_waitcnt vmcnt(" #N ")" ::: "memory");         \
                      __builtin_amdgcn_s_barrier(); SB(); }

    // Stage one 4-koct sub-chunk of B (8 KB) into buffer BUF: 1 DMA per wave.
    #define STAGE(BUF, KOCT0) {                                                     \
        const int nt = w & 3;                                                       \
        const ushort* srcp = ((w >> 2) ? wlo : whi)                                 \
            + ((size_t)(ntile0 + nt) * 32 + (KOCT0) + (lane >> 4)) * 128            \
            + (lane & 15) * 8;                                                      \
        ushort* dstp = ((w >> 2) ? sBl : sBh) + (BUF) * 2048 + nt * 512;            \
        __builtin_amdgcn_global_load_lds((as1_uint*)srcp, (as3_uint*)dstp,          \
                                         16, 0, 0);                                 \
        SB();  /* pin: DMA issues before the A-loads that follow */                 \
    }

    // prefetch A fragments for the 1 k-step of sub-chunk at KOCT0 into regs
    #define APREF(AH, AL, KOCT0) {                                                  \
        const int koct = (KOCT0) + lquad;                                           \
        _Pragma("unroll")                                                           \
        for (int mi = 0; mi < 2; ++mi) {                                            \
            const size_t o = ((size_t)(btile0 + mi) * 32 + koct) * 128 + l16 * 8;   \
            AH[mi] = *(const bf16x8*)(xhi + o);                                     \
            AL[mi] = *(const bf16x8*)(xlo + o);                                     \
        }                                                                           \
    }

    // 1 MFMA k-step over buffer BUF using prefetched A regs (24 MFMAs/wave)
    #define KSTEP(BUF, AH, AL) {                                                    \
        const int bidx = (BUF) * 2048 + lquad * 128 + l16 * 8;                      \
        bf16x8 bH[4], bL[4];                                                        \
        _Pragma("unroll")                                                           \
        for (int ni = 0; ni < 4; ++ni) {                                            \
            bH[ni] = *(const bf16x8*)(sBh + ni * 512 + bidx);                       \
            bL[ni] = *(const bf16x8*)(sBl + ni * 512 + bidx);                       \
        }                                                                           \
        _Pragma("unroll")                                                           \
        for (int mi = 0; mi < 2; ++mi)                                              \
            _Pragma("unroll")                                                       \
            for (int ni = 0; ni < 4; ++ni)                                          \
                acc[mi][ni] = __builtin_amdgcn_mfma_f32_16x16x32_bf16(bH[ni], AH[mi], acc[mi][ni], 0, 0, 0); \
        _Pragma("unroll")                                                           \
        for (int mi = 0; mi < 2; ++mi)                                              \
            _Pragma("unroll")                                                       \
            for (int ni = 0; ni < 4; ++ni)                                          \
                acc[mi][ni] = __builtin_amdgcn_mfma_f32_16x16x32_bf16(bH[ni], AL[mi], acc[mi][ni], 0, 0, 0); \
        _Pragma("unroll")                                                           \
        for (int mi = 0; mi < 2; ++mi)                                              \
            _Pragma("unroll")                                                       \
            for (int ni = 0; ni < 4; ++ni)                                          \
                acc[mi][ni] = __builtin_amdgcn_mfma_f32_16x16x32_bf16(bL[ni], AH[mi], acc[mi][ni], 0, 0, 0); \
    }

    bf16x8 AaH[2], AaL[2], AbH[2], AbL[2];
    fvec4 hv[2][4];

    // 8 sub-chunks of 4 koct. Phase = STAGE(next-buf) ; APREF ; KSTEP(cur) ;
    // counted barrier (own DMA done, A-loads may fly).
    STAGE(0, 0);   APREF(AaH, AaL, 0);
    BARC(4);                                // DMA0 done; Aa(4) in flight
    STAGE(1, 4);   APREF(AbH, AbL, 4);
    KSTEP(0, AaH, AaL);                     // DMA1 + Ab fly under compute
    BARC(4);
    STAGE(0, 8);   APREF(AaH, AaL, 8);
    KSTEP(1, AbH, AbL);
    BARC(4);
    STAGE(1, 12);  APREF(AbH, AbL, 12);
    KSTEP(0, AaH, AaL);
    BARC(4);
    STAGE(0, 16);  APREF(AaH, AaL, 16);
    KSTEP(1, AbH, AbL);
    BARC(4);
    STAGE(1, 20);  APREF(AbH, AbL, 20);
    KSTEP(0, AaH, AaL);
    BARC(4);
    STAGE(0, 24);  APREF(AaH, AaL, 24);
    KSTEP(1, AbH, AbL);
    BARC(4);
    STAGE(1, 28);  APREF(AbH, AbL, 28);
    // epilogue hq prefetch (cached): flies under the last two k-steps
    #pragma unroll
    for (int mi = 0; mi < 2; ++mi) {
        const int b = row0 + w * 32 + mi * 16 + l16;
        #pragma unroll
        for (int ni = 0; ni < 4; ++ni) {
            const int n = col0 + ni * 16 + lquad * 4;
            hv[mi][ni] = *(const fvec4*)&hq[(size_t)b * NCOL + n];
        }
    }
    KSTEP(0, AaH, AaL);
    BARC(12);                               // DMA(28) done; Ab(4)+hv(8) fly
    KSTEP(1, AbH, AbL);
    #undef STAGE
    #undef APREF
    #undef KSTEP
    #undef BARC
    #undef SB

    // ---- fused epilogue: tanh(C + 0.9*h), nt out_new store, cached out_mean.
    //      D[n][b]: n = col0+ni*16+4*lquad+reg, b = row0+w*32+mi*16+l16
    #pragma unroll
    for (int mi = 0; mi < 2; ++mi) {
        const int b = row0 + w * 32 + mi * 16 + l16;
        #pragma unroll
        for (int ni = 0; ni < 4; ++ni) {
            const int n = col0 + ni * 16 + lquad * 4;
            fvec4 ov;
            ov.x = tanh_fast(__builtin_fmaf(0.9f, hv[mi][ni].x, acc[mi][ni][0]));
            ov.y = tanh_fast(__builtin_fmaf(0.9f, hv[mi][ni].y, acc[mi][ni][1]));
            ov.z = tanh_fast(__builtin_fmaf(0.9f, hv[mi][ni].z, acc[mi][ni][2]));
            ov.w = tanh_fast(__builtin_fmaf(0.9f, hv[mi][ni].w, acc[mi][ni][3]));
            __builtin_nontemporal_store(ov, (fvec4*)&out_new[(size_t)b * NCOL + n]);
            float s = (ov.x + ov.y) + (ov.z + ov.w);
            s += __shfl_xor(s, 16);
            s += __shfl_xor(s, 32);
            if (lquad == 0)
                out_mean[(size_t)b * HID + (col0 >> 4) + ni] = s * 0.0625f;
        }
    }
}

// ================= fallback (round-5 proven kernel, used if ws too small) ======
#define BMF 128
#define BKF 64
__device__ __forceinline__ int swz(int row, int byteoff) {
    return byteoff ^ ((((row & 7) ^ ((row >> 3) & 7))) << 4);
}
__global__ __launch_bounds__(256, 4) void mqc_fallback_kernel(
    const float* __restrict__ x, const float* __restrict__ hq,
    const float* __restrict__ W,
    float* __restrict__ out_mean, float* __restrict__ out_new)
{
    __shared__ char sB[2 * BN * BKF * 2];
    char* const sB_hi = sB;
    char* const sB_lo = sB + BN * BKF * 2;
    const int t = threadIdx.x, lane = t & 63, w = t >> 6;
    const int lquad = lane >> 4, l16 = lane & 15;
    const int row0 = blockIdx.x * BMF, col0 = blockIdx.y * BN;
    const int k0 = (t >> 4) * 4, n0 = (t & 15) * 4;
    f32x4 acc[2][4] = {};
    for (int kt = 0; kt < IN_DIM / BKF; ++kt) {
        float4 ax[2][2][2];
        #pragma unroll
        for (int mi = 0; mi < 2; ++mi)
            #pragma unroll
            for (int ks = 0; ks < 2; ++ks) {
                const float* p = &x[(size_t)(row0 + w * 32 + mi * 16 + l16) * IN_DIM
                                    + kt * BKF + ks * 32 + lquad * 8];
                ax[mi][ks][0] = *(const float4*)(p);
                ax[mi][ks][1] = *(const float4*)(p + 4);
            }
        float4 wrow[4];
        #pragma unroll
        for (int r = 0; r < 4; ++r)
            wrow[r] = *(const float4*)(&W[(size_t)(kt * BKF + k0 + r) * NCOL + col0 + n0]);
        #pragma unroll
        for (int c = 0; c < 4; ++c) {
            const float f0 = ((const float*)&wrow[0])[c];
            const float f1 = ((const float*)&wrow[1])[c];
            const float f2 = ((const float*)&wrow[2])[c];
            const float f3 = ((const float*)&wrow[3])[c];
            uint2 hv2, lv2;
            hv2.x = pack_hi(f0, f1); hv2.y = pack_hi(f2, f3);
            lv2.x = pack_hi(f0 - hi_part(f0), f1 - hi_part(f1));
            lv2.y = pack_hi(f2 - hi_part(f2), f3 - hi_part(f3));
            const int off = swz(n0 + c, (n0 + c) * (BKF * 2) + k0 * 2);
            *(uint2*)(sB_hi + off) = hv2;
            *(uint2*)(sB_lo + off) = lv2;
        }
        __syncthreads();
        #pragma unroll
        for (int ks = 0; ks < 2; ++ks) {
            bf16x8 aH[2], aL[2];
            #pragma unroll
            for (int mi = 0; mi < 2; ++mi) {
                uint4 h, l;
                split8((const float*)&ax[mi][ks][0], h, l);
                aH[mi] = __builtin_bit_cast(bf16x8, h);
                aL[mi] = __builtin_bit_cast(bf16x8, l);
            }
            const int kb = ks * 64 + lquad * 16;
            bf16x8 bH[4], bL[4];
            #pragma unroll
            for (int ni = 0; ni < 4; ++ni) {
                const int row = ni * 16 + l16;
                bH[ni] = *(const bf16x8*)(sB_hi + swz(row, row * (BKF * 2) + kb));
            }
            #pragma unroll
            for (int mi = 0; mi < 2; ++mi)
                #pragma unroll
                for (int ni = 0; ni < 4; ++ni)
                    acc[mi][ni] = __builtin_amdgcn_mfma_f32_16x16x32_bf16(bH[ni], aH[mi], acc[mi][ni], 0, 0, 0);
            #pragma unroll
            for (int mi = 0; mi < 2; ++mi)
                #pragma unroll
                for (int ni = 0; ni < 4; ++ni)
                    acc[mi][ni] = __builtin_amdgcn_mfma_f32_16x16x32_bf16(bH[ni], aL[mi], acc[mi][ni], 0, 0, 0);
            #pragma unroll
            for (int ni = 0; ni < 4; ++ni) {
                const int row = ni * 16 + l16;
                bL[ni] = *(const bf16x8*)(sB_lo + swz(row, row * (BKF * 2) + kb));
            }
            #pragma unroll
            for (int mi = 0; mi < 2; ++mi)
                #pragma unroll
                for (int ni = 0; ni < 4; ++ni)
                    acc[mi][ni] = __builtin_amdgcn_mfma_f32_16x16x32_bf16(bL[ni], aH[mi], acc[mi][ni], 0, 0, 0);
        }
        __syncthreads();
    }
    #pragma unroll
    for (int mi = 0; mi < 2; ++mi) {
        const int b = row0 + w * 32 + mi * 16 + l16;
        #pragma unroll
        for (int ni = 0; ni < 4; ++ni) {
            const int n = col0 + ni * 16 + lquad * 4;
            const float4 hv = *(const float4*)(&hq[(size_t)b * NCOL + n]);
            float4 ov;
            ov.x = tanh_fast(__builtin_fmaf(0.9f, hv.x, acc[mi][ni][0]));
            ov.y = tanh_fast(__builtin_fmaf(0.9f, hv.y, acc[mi][ni][1]));
            ov.z = tanh_fast(__builtin_fmaf(0.9f, hv.z, acc[mi][ni][2]));
            ov.w = tanh_fast(__builtin_fmaf(0.9f, hv.w, acc[mi][ni][3]));
            *(float4*)(&out_new[(size_t)b * NCOL + n]) = ov;
            float s = (ov.x + ov.y) + (ov.z + ov.w);
            s += __shfl_xor(s, 16);
            s += __shfl_xor(s, 32);
            if (lquad == 0)
                out_mean[(size_t)b * HID + (col0 >> 4) + ni] = s * 0.0625f;
        }
    }
}

extern "C" void kernel_launch(void* const* d_in, const int* in_sizes, int n_in,
                              void* d_out, int out_size, void* d_ws, size_t ws_size,
                              hipStream_t stream) {
    const float* x  = (const float*)d_in[0];   // [4096, 256]
    const float* hq = (const float*)d_in[1];   // [4096, 512, 16]
    const float* W  = (const float*)d_in[2];   // [256, 512, 16]

    float* out_mean = (float*)d_out;                          // [4096, 512]
    float* out_new  = (float*)d_out + (size_t)BATCH * HID;    // [4096, 512, 16]

    if (ws_size >= WS_NEED) {
        ushort* whi = (ushort*)d_ws;
        ushort* wlo = whi + W_ELEMS;
        ushort* xhi = wlo + W_ELEMS;
        ushort* xlo = xhi + X_ELEMS;
        prep_kernel<<<dim3(1536), 256, 0, stream>>>(W, x, whi, wlo, xhi, xlo);
        mqc_main_kernel<<<dim3(BATCH * NCOL / (BM * BN)), 512, 0, stream>>>(
            xhi, xlo, whi, wlo, hq, out_mean, out_new);
    } else {
        mqc_fallback_kernel<<<dim3(BATCH / BMF, NCOL / BN), 256, 0, stream>>>(
            x, hq, W, out_mean, out_new);
    }
}